// Round 8
// baseline (2709.419 us; speedup 1.0000x reference)
//
#include <hip/hip_runtime.h>
#include <hip/hip_bf16.h>

typedef short bf16x8 __attribute__((ext_vector_type(8)));
typedef float f32x4 __attribute__((ext_vector_type(4)));
typedef float f32x16 __attribute__((ext_vector_type(16)));
typedef unsigned int u32x4 __attribute__((ext_vector_type(4)));

typedef __attribute__((address_space(1))) void gvoid;
typedef __attribute__((address_space(3))) void lvoid;

__device__ __forceinline__ short f2b(float f) {
  __hip_bfloat16 h = __float2bfloat16(f);
  return __builtin_bit_cast(short, h);
}

__device__ __forceinline__ f32x4 mfma16(bf16x8 a, bf16x8 b, f32x4 c) {
  return __builtin_amdgcn_mfma_f32_16x16x32_bf16(a, b, c, 0, 0, 0);
}

__device__ __forceinline__ f32x16 mfma32(bf16x8 a, bf16x8 b, f32x16 c) {
  return __builtin_amdgcn_mfma_f32_32x32x16_bf16(a, b, c, 0, 0, 0);
}

__device__ __forceinline__ unsigned cvtpk(float lo, float hi) {
  unsigned r;
  asm("v_cvt_pk_bf16_f32 %0, %1, %2" : "=v"(r) : "v"(lo), "v"(hi));
  return r;
}

__device__ __forceinline__ void gload16(const void* g, void* l) {
  __builtin_amdgcn_global_load_lds((const gvoid*)g, (lvoid*)l, 16, 0, 0);
}

// ---------------------------------------------------------------- weights
__global__ __launch_bounds__(256) void convT_k(const float* __restrict__ src,
                                               short* __restrict__ dst, int K,
                                               int N, int scale_cols,
                                               float scale) {
  int idx = blockIdx.x * 256 + threadIdx.x;
  if (idx >= N * K) return;
  int n = idx / K, k = idx % K;
  float v = src[(size_t)k * N + n];
  if (n < scale_cols) v *= scale;
  dst[idx] = f2b(v);
}

__global__ __launch_bounds__(256) void scale_bias_k(const float* __restrict__ src,
                                                    float* __restrict__ dst,
                                                    int n, int scale_cols,
                                                    float scale) {
  int i = blockIdx.x * 256 + threadIdx.x;
  if (i >= n) return;
  dst[i] = src[i] * (i < scale_cols ? scale : 1.f);
}

// Combined rel-pos bias + shift mask table: tbl[cls][h][key][query], f32.
__global__ __launch_bounds__(256) void biasmask_k(const float* __restrict__ rpb,
                                                  float* __restrict__ tbl) {
  int idx = blockIdx.x * 256 + threadIdx.x;  // < 4*12*64*64
  int q = idx & 63, key = (idx >> 6) & 63;
  int hc = idx >> 12;  // cls*12 + h
  int h = hc % 12, cls = hc / 12;
  float v;
  if (q >= 49 || key >= 49) {
    v = -1e4f;
  } else {
    int i1 = q / 7, j1 = q % 7, i2 = key / 7, j2 = key % 7;
    v = rpb[(size_t)((i1 - i2 + 6) * 13 + (j1 - j2 + 6)) * 12 + h];
    int clsh = cls >> 1, clsw = cls & 1;
    int rq = (clsh ? 1 + (i1 >= 4) : 0) * 3 + (clsw ? 1 + (j1 >= 4) : 0);
    int rk = (clsh ? 1 + (i2 >= 4) : 0) * 3 + (clsw ? 1 + (j2 >= 4) : 0);
    if (rq != rk) v -= 100.f;
  }
  tbl[idx] = v;
}

// ---------------------------------------------------------------- layernorm
template <bool GATHER>
__device__ __forceinline__ void ln_body(const float* __restrict__ x,
                                        const float* __restrict__ gw,
                                        const float* __restrict__ bw,
                                        short* __restrict__ out) {
  const int lane = threadIdx.x & 63;
  const int t = (blockIdx.x << 2) + (threadIdx.x >> 6);
  size_t srow;
  if (GATHER) {
    int bb = t / 12544, rm2 = t % 12544;
    int wi = rm2 / 49, nn = rm2 % 49;
    int wh = wi >> 4, ww = wi & 15;
    int ii = nn / 7, jj = nn % 7;
    int rr = wh * 7 + ii + 3; if (rr >= 112) rr -= 112;
    int cc = ww * 7 + jj + 3; if (cc >= 112) cc -= 112;
    srow = ((size_t)bb * 12544 + rr * 112 + cc) * 384;
  } else {
    srow = (size_t)t * 384;
  }
  const float2* src = (const float2*)(x + srow);
  const float2* g2 = (const float2*)gw;
  const float2* b2 = (const float2*)bw;
  float2 u[3];
  float s = 0.f, ss = 0.f;
#pragma unroll
  for (int k = 0; k < 3; ++k) {
    u[k] = src[lane + (k << 6)];
    s += u[k].x + u[k].y;
    ss += u[k].x * u[k].x + u[k].y * u[k].y;
  }
#pragma unroll
  for (int m = 1; m < 64; m <<= 1) {
    s += __shfl_xor(s, m, 64);
    ss += __shfl_xor(ss, m, 64);
  }
  const float mean = s * (1.f / 384.f);
  const float var = ss * (1.f / 384.f) - mean * mean;
  const float rstd = rsqrtf(var + 1e-5f);
  unsigned* o = (unsigned*)(out + (size_t)t * 384);
#pragma unroll
  for (int k = 0; k < 3; ++k) {
    int c = lane + (k << 6);
    float2 gv = g2[c], bv = b2[c];
    unsigned lo = (unsigned short)f2b((u[k].x - mean) * rstd * gv.x + bv.x);
    unsigned hi = (unsigned short)f2b((u[k].y - mean) * rstd * gv.y + bv.y);
    o[c] = lo | (hi << 16);
  }
}

__global__ __launch_bounds__(256) void ln1_k(const float* __restrict__ x,
                                             const float* __restrict__ gw,
                                             const float* __restrict__ bw,
                                             short* __restrict__ out) {
  ln_body<true>(x, gw, bw, out);
}
__global__ __launch_bounds__(256) void ln2_k(const float* __restrict__ x,
                                             const float* __restrict__ gw,
                                             const float* __restrict__ bw,
                                             short* __restrict__ out) {
  ln_body<false>(x, gw, bw, out);
}

// ---------------------------------------------------------------- GEMM
// 128x128 tile, BK=32, 4 waves (2x2). A staged in LDS ring-3 (8KB/slot,
// 24KB total) with 2-way chunk swizzle (free per m136): source chunk
// cswz=(tid&3)^((tid>>3)&3), read chunk pos g^((q>>1)&3). B (weights,
// L2-resident: 0.3-1.2MB) loaded DIRECT to registers, double-buffered
// one phase ahead -- halves LDS pipe traffic and stage ops. Per phase:
// BLOAD(t+1)[4 vm ops]; STAGE_A(t+2)[2 vm ops]; COMPUTE(t);
// vmcnt(2) (forces bf(t+1)+stageA(t+1) complete, keeps stageA(t+2) in
// flight); s_barrier. 6-phase unroll (bf dbuf 2 x A ring 3); nt%6==0.
template <int EPI>
__device__ __forceinline__ void gemm_body(
    const short* __restrict__ A, int lda, const short* __restrict__ BT,
    int ldb, const float* __restrict__ bias, int K, short* __restrict__ outh,
    int ldo, float* __restrict__ outf, const float* __restrict__ resid) {
  __shared__ __align__(16) short A0s[4096];
  __shared__ __align__(16) short A1s[4096];
  __shared__ __align__(16) short A2s[4096];
  const int tid = threadIdx.x;
  const int gx = gridDim.x;
  int lin = blockIdx.y * gx + blockIdx.x;
  const int cpx = (gx * gridDim.y) >> 3;
  lin = (lin & 7) * cpx + (lin >> 3);
  const int m0 = (lin / gx) << 7, n0 = (lin % gx) << 7;
  const int lane = tid & 63;
  const int wave = tid >> 6;
  const int wr = (wave >> 1) << 6, wc = (wave & 1) << 6;
  const int g = lane >> 4, q = lane & 15;
  const int loff = tid << 3;
  const int cswz = (tid & 3) ^ ((tid >> 3) & 3);   // source-side chunk
  const int cpos = (g ^ ((q >> 1) & 3)) << 3;      // read-side chunk pos

  f32x4 acc[4][4];
#pragma unroll
  for (int i = 0; i < 4; ++i)
#pragma unroll
    for (int j = 0; j < 4; ++j) acc[i][j] = (f32x4){0.f, 0.f, 0.f, 0.f};

  const short* Ab = A + (size_t)(m0 + (tid >> 2)) * lda + cswz * 8;
  const short* Ab2 = Ab + (size_t)64 * lda;
  const short* Bq = BT + (size_t)(n0 + wc + q) * ldb + g * 8;  // + ni*16*ldb + kt
  const size_t bstep = (size_t)16 * ldb;

#define STAGE_A(kt, DA)                    \
  do {                                     \
    gload16(Ab + (kt), &DA[loff]);         \
    gload16(Ab2 + (kt), &DA[loff + 2048]); \
  } while (0)

#define BLOAD(BF, kt)                                                     \
  do {                                                                    \
    _Pragma("unroll") for (int ni = 0; ni < 4; ++ni)                      \
        BF[ni] = *(const bf16x8*)(Bq + (size_t)ni * bstep + (kt));        \
  } while (0)

#define COMPUTE(SA, BF)                                                   \
  do {                                                                    \
    bf16x8 af[4];                                                         \
    _Pragma("unroll") for (int mi = 0; mi < 4; ++mi)                      \
        af[mi] = *(const bf16x8*)&SA[(wr + mi * 16 + q) * 32 + cpos];     \
    _Pragma("unroll") for (int mi = 0; mi < 4; ++mi)                      \
        _Pragma("unroll") for (int ni = 0; ni < 4; ++ni)                  \
            acc[mi][ni] = mfma16(af[mi], BF[ni], acc[mi][ni]);            \
  } while (0)

#define VMW2                                          \
  do {                                                \
    asm volatile("s_waitcnt vmcnt(2)" ::: "memory");  \
    __builtin_amdgcn_sched_barrier(0);                \
  } while (0)
#define VMW0                                          \
  do {                                                \
    asm volatile("s_waitcnt vmcnt(0)" ::: "memory");  \
    __builtin_amdgcn_sched_barrier(0);                \
  } while (0)
#define BAR __builtin_amdgcn_s_barrier()

  bf16x8 bfA[4], bfB[4];
  const int nt = K >> 5;  // 12, 24, or 48: %6==0, >=12

  // prologue: bf(0), A-tiles 0,1 (tile-1 stage left in flight)
  BLOAD(bfA, 0);
  STAGE_A(0, A0s);
  STAGE_A(32, A1s);
  VMW2;
  BAR;

#define PH(BFC, BFN, SCUR, SNXT, tt)     \
  do {                                   \
    BLOAD(BFN, ((tt) + 1) << 5);         \
    STAGE_A(((tt) + 2) << 5, SNXT);      \
    COMPUTE(SCUR, BFC);                  \
    VMW2;                                \
    BAR;                                 \
  } while (0)

  int t = 0;
  for (; t + 6 < nt; t += 6) {
    PH(bfA, bfB, A0s, A2s, t + 0);
    PH(bfB, bfA, A1s, A0s, t + 1);
    PH(bfA, bfB, A2s, A1s, t + 2);
    PH(bfB, bfA, A0s, A2s, t + 3);
    PH(bfA, bfB, A1s, A0s, t + 4);
    PH(bfB, bfA, A2s, A1s, t + 5);
  }
  // final 6 phases (t = nt-6): last two have no stage / no bload
  PH(bfA, bfB, A0s, A2s, t + 0);
  PH(bfB, bfA, A1s, A0s, t + 1);
  PH(bfA, bfB, A2s, A1s, t + 2);
  PH(bfB, bfA, A0s, A2s, t + 3);
  // phase nt-2: bload(nt-1) only, then drain everything
  BLOAD(bfB, (t + 5) << 5);
  COMPUTE(A1s, bfA);
  VMW0;
  BAR;
  // phase nt-1
  COMPUTE(A2s, bfB);
#undef STAGE_A
#undef BLOAD
#undef COMPUTE
#undef VMW2
#undef VMW0
#undef BAR
#undef PH

  float bv[4];
#pragma unroll
  for (int ni = 0; ni < 4; ++ni)
    bv[ni] = bias ? bias[n0 + wc + ni * 16 + q] : 0.f;

#pragma unroll
  for (int mi = 0; mi < 4; ++mi) {
#pragma unroll
    for (int r = 0; r < 4; ++r) {
      const int grow = m0 + wr + mi * 16 + g * 4 + r;
      size_t orow;
      if constexpr (EPI == 2) {
        int bb = grow / 12544, rm2 = grow % 12544;
        int wi = rm2 / 49, nn = rm2 % 49;
        int wh = wi >> 4, ww = wi & 15;
        int ii = nn / 7, jj = nn % 7;
        int rr = wh * 7 + ii + 3; if (rr >= 112) rr -= 112;
        int cc = ww * 7 + jj + 3; if (cc >= 112) cc -= 112;
        orow = ((size_t)bb * 12544 + rr * 112 + cc) * 384;
      } else {
        orow = (size_t)grow * (size_t)ldo;
      }
#pragma unroll
      for (int ni = 0; ni < 4; ++ni) {
        const int gcol = n0 + wc + ni * 16 + q;
        float v = acc[mi][ni][r] + bv[ni];
        if constexpr (EPI == 0) {
          outh[orow + gcol] = f2b(v);
        } else if constexpr (EPI == 1) {
          v = 0.5f * v * (1.f + erff(v * 0.70710678118f));
          outh[orow + gcol] = f2b(v);
        } else if constexpr (EPI == 2) {
          outf[orow + gcol] = resid[orow + gcol] + v;
        } else {
          outf[orow + gcol] += v;
        }
      }
    }
  }
}

#define GEMM_WRAP(NAME, EPI)                                                   \
  __global__ __launch_bounds__(256) void NAME(                                 \
      const short* __restrict__ A, int lda, const short* __restrict__ BT,      \
      int ldb, const float* __restrict__ bias, int K,                          \
      short* __restrict__ outh, int ldo, float* __restrict__ outf,             \
      const float* __restrict__ resid) {                                       \
    gemm_body<EPI>(A, lda, BT, ldb, bias, K, outh, ldo, outf, resid);          \
  }
GEMM_WRAP(gemm_qkv_k, 0)
GEMM_WRAP(gemm_fc1_k, 1)
GEMM_WRAP(gemm_proj_k, 2)
GEMM_WRAP(gemm_fc2_k, 3)

// ---------------------------------------------------------------- attention
// One wave per (window, head), 4 waves/block, ZERO LDS. Swapped QK^T via
// mfma_32x32x16; in-register softmax; cvt_pk + shfl_xor(32) assembles PV
// A-frags (T12); V^T B-frags straight from global; bias+mask from table.
__global__ __launch_bounds__(256) void attn_k(const short* __restrict__ qkv,
                                              const float* __restrict__ tbl,
                                              short* __restrict__ out) {
  const int lane = threadIdx.x & 63;
  const int task = blockIdx.x * 4 + (threadIdx.x >> 6);
  const int win = task / 12;
  const int h = task - win * 12;
  const int wh = (win >> 4) & 15, ww = win & 15;
  const int cls = ((wh == 15) ? 2 : 0) + ((ww == 15) ? 1 : 0);
  const int l31 = lane & 31, h5 = lane >> 5;
  const size_t tokbase = (size_t)win * 49;
  const short* base = qkv + tokbase * 1152 + h * 32;
  const bf16x8 zero8 = {0, 0, 0, 0, 0, 0, 0, 0};

  bf16x8 kf[2][2];
#pragma unroll
  for (int mi = 0; mi < 2; ++mi) {
    int row = l31 + 32 * mi;
#pragma unroll
    for (int s = 0; s < 2; ++s)
      kf[mi][s] = (row < 49)
                      ? *(const bf16x8*)(base + (size_t)row * 1152 + 384 +
                                         16 * s + 8 * h5)
                      : zero8;
  }
  bf16x8 vf[4];
#pragma unroll
  for (int kt = 0; kt < 4; ++kt) {
#pragma unroll
    for (int e = 0; e < 8; ++e) {
      int key = 16 * kt + 8 * h5 + e;
      vf[kt][e] = (key < 49) ? base[(size_t)key * 1152 + 768 + l31] : (short)0;
    }
  }

  const float* tb = tbl + ((size_t)(cls * 12 + h) << 12);

#pragma unroll
  for (int ni = 0; ni < 2; ++ni) {
    bf16x8 qf[2];
    int qrow = l31 + 32 * ni;
#pragma unroll
    for (int s = 0; s < 2; ++s)
      qf[s] = (qrow < 49)
                  ? *(const bf16x8*)(base + (size_t)qrow * 1152 + 16 * s +
                                     8 * h5)
                  : zero8;
    f32x16 st[2];
#pragma unroll
    for (int mi = 0; mi < 2; ++mi) {
      st[mi] = mfma32(kf[mi][0], qf[0], (f32x16)(0.f));
      st[mi] = mfma32(kf[mi][1], qf[1], st[mi]);
    }
#pragma unroll
    for (int mi = 0; mi < 2; ++mi)
#pragma unroll
      for (int r = 0; r < 16; ++r) {
        int koff = (r & 3) + 8 * (r >> 2) + 4 * h5;
        st[mi][r] += tb[(size_t)(32 * mi + koff) * 64 + 32 * ni + l31];
      }
    float mx = st[0][0];
#pragma unroll
    for (int r = 1; r < 16; ++r) mx = fmaxf(mx, st[0][r]);
#pragma unroll
    for (int r = 0; r < 16; ++r) mx = fmaxf(mx, st[1][r]);
    mx = fmaxf(mx, __shfl_xor(mx, 32, 64));
    float sm = 0.f;
#pragma unroll
    for (int mi = 0; mi < 2; ++mi)
#pragma unroll
      for (int r = 0; r < 16; ++r) {
        float e = __expf(st[mi][r] - mx);
        st[mi][r] = e;
        sm += e;
      }
    sm += __shfl_xor(sm, 32, 64);
    const float rinv = 1.f / sm;
#pragma unroll
    for (int mi = 0; mi < 2; ++mi)
#pragma unroll
      for (int r = 0; r < 16; ++r) st[mi][r] *= rinv;

    f32x16 acc = (f32x16)(0.f);
#pragma unroll
    for (int kt = 0; kt < 4; ++kt) {
      const int mi = kt >> 1, b8 = (kt & 1) * 8;
      unsigned q0l = cvtpk(st[mi][b8 + 0], st[mi][b8 + 1]);
      unsigned q0h = cvtpk(st[mi][b8 + 2], st[mi][b8 + 3]);
      unsigned q1l = cvtpk(st[mi][b8 + 4], st[mi][b8 + 5]);
      unsigned q1h = cvtpk(st[mi][b8 + 6], st[mi][b8 + 7]);
      unsigned sl = h5 ? q0l : q1l, sh = h5 ? q0h : q1h;
      unsigned kl = h5 ? q1l : q0l, kh = h5 ? q1h : q0h;
      unsigned rl = (unsigned)__shfl_xor((int)sl, 32, 64);
      unsigned rh = (unsigned)__shfl_xor((int)sh, 32, 64);
      u32x4 fr;
      fr[0] = h5 ? rl : kl;
      fr[1] = h5 ? rh : kh;
      fr[2] = h5 ? kl : rl;
      fr[3] = h5 ? kh : rh;
      acc = mfma32(__builtin_bit_cast(bf16x8, fr), vf[kt], acc);
    }
#pragma unroll
    for (int r = 0; r < 16; ++r) {
      int query = 32 * ni + (r & 3) + 8 * (r >> 2) + 4 * h5;
      if (ni == 0 || query < 49)
        out[(tokbase + query) * 384 + h * 32 + l31] = f2b(acc[r]);
    }
  }
}

// ---------------------------------------------------------------- launch
extern "C" void kernel_launch(void* const* d_in, const int* in_sizes, int n_in,
                              void* d_out, int out_size, void* d_ws,
                              size_t ws_size, hipStream_t stream) {
  const float* x = (const float*)d_in[0];
  const float* n1g = (const float*)d_in[1];
  const float* n1b = (const float*)d_in[2];
  const float* qkvw = (const float*)d_in[3];
  const float* qkvb = (const float*)d_in[4];
  const float* projw = (const float*)d_in[5];
  const float* projb = (const float*)d_in[6];
  const float* rpb = (const float*)d_in[7];
  const float* n2g = (const float*)d_in[8];
  const float* n2b = (const float*)d_in[9];
  const float* fc1w = (const float*)d_in[10];
  const float* fc1b = (const float*)d_in[11];
  const float* fc2w = (const float*)d_in[12];
  const float* fc2b = (const float*)d_in[13];
  float* out = (float*)d_out;

  char* ws = (char*)d_ws;
  short* w_qkvT = (short*)(ws + 0);            // 884736 B
  short* w_projT = (short*)(ws + 884736);      // 294912 B
  short* w_fc1T = (short*)(ws + 1179648);      // 1179648 B
  short* w_fc2T = (short*)(ws + 2359296);      // 1179648 B
  float* w_qb = (float*)(ws + 3538944);        // 4608 B
  float* tbl = (float*)(ws + 3543552);         // 786432 B
  const size_t o_qkv = 4329984;
  short* qkvbuf = (short*)(ws + o_qkv);        // 462422016 B
  const size_t o_hwin = o_qkv + 462422016ull;
  short* hwin = (short*)(ws + o_hwin);         // 154140672 B
  const size_t o_fc1 = o_hwin + 154140672ull;

  int NC;
  size_t fc1_off = o_fc1;
  if (ws_size >= o_fc1 + 616562688ull) NC = 1;
  else if (ws_size >= o_fc1 + 308281344ull) NC = 2;
  else if (ws_size >= o_fc1 + 154140672ull) NC = 4;
  else { NC = 4; fc1_off = o_hwin; }
  short* fc1c = (short*)(ws + fc1_off);
  short* h2 = qkvbuf;

  const float qscale = 0.17677669529663687f;

  convT_k<<<(442368 + 255) / 256, 256, 0, stream>>>(qkvw, w_qkvT, 384, 1152, 384, qscale);
  convT_k<<<(147456 + 255) / 256, 256, 0, stream>>>(projw, w_projT, 384, 384, 0, 1.f);
  convT_k<<<(589824 + 255) / 256, 256, 0, stream>>>(fc1w, w_fc1T, 384, 1536, 0, 1.f);
  convT_k<<<(589824 + 255) / 256, 256, 0, stream>>>(fc2w, w_fc2T, 1536, 384, 0, 1.f);
  scale_bias_k<<<5, 256, 0, stream>>>(qkvb, w_qb, 1152, 384, qscale);
  biasmask_k<<<768, 256, 0, stream>>>(rpb, tbl);

  ln1_k<<<50176, 256, 0, stream>>>(x, n1g, n1b, hwin);
  gemm_qkv_k<<<dim3(9, 1568), 256, 0, stream>>>(hwin, 384, w_qkvT, 384, w_qb,
                                                384, qkvbuf, 1152, nullptr,
                                                nullptr);
  attn_k<<<12288, 256, 0, stream>>>(qkvbuf, tbl, hwin);
  gemm_proj_k<<<dim3(3, 1568), 256, 0, stream>>>(hwin, 384, w_projT, 384,
                                                 projb, 384, nullptr, 384, out,
                                                 x);
  ln2_k<<<50176, 256, 0, stream>>>(out, n2g, n2b, h2);
  const int CK = 1536 / NC;
  for (int c = 0; c < NC; ++c) {
    gemm_fc1_k<<<dim3(CK >> 7, 1568), 256, 0, stream>>>(
        h2, 384, w_fc1T + (size_t)c * CK * 384, 384, fc1b + c * CK, 384, fc1c,
        CK, nullptr, nullptr);
    gemm_fc2_k<<<dim3(3, 1568), 256, 0, stream>>>(
        fc1c, CK, w_fc2T + c * CK, 1536, (c == 0) ? fc2b : nullptr, CK,
        nullptr, 384, out, nullptr);
  }
}

// Round 9
// 2127.866 us; speedup vs baseline: 1.2733x; 1.2733x over previous
//
#include <hip/hip_runtime.h>
#include <hip/hip_bf16.h>

typedef short bf16x8 __attribute__((ext_vector_type(8)));
typedef float f32x4 __attribute__((ext_vector_type(4)));
typedef float f32x16 __attribute__((ext_vector_type(16)));
typedef unsigned int u32x4 __attribute__((ext_vector_type(4)));

typedef __attribute__((address_space(1))) void gvoid;
typedef __attribute__((address_space(3))) void lvoid;

__device__ __forceinline__ short f2b(float f) {
  __hip_bfloat16 h = __float2bfloat16(f);
  return __builtin_bit_cast(short, h);
}

__device__ __forceinline__ f32x4 mfma16(bf16x8 a, bf16x8 b, f32x4 c) {
  return __builtin_amdgcn_mfma_f32_16x16x32_bf16(a, b, c, 0, 0, 0);
}

__device__ __forceinline__ f32x16 mfma32(bf16x8 a, bf16x8 b, f32x16 c) {
  return __builtin_amdgcn_mfma_f32_32x32x16_bf16(a, b, c, 0, 0, 0);
}

__device__ __forceinline__ unsigned cvtpk(float lo, float hi) {
  unsigned r;
  asm("v_cvt_pk_bf16_f32 %0, %1, %2" : "=v"(r) : "v"(lo), "v"(hi));
  return r;
}

__device__ __forceinline__ void gload16(const void* g, void* l) {
  __builtin_amdgcn_global_load_lds((const gvoid*)g, (lvoid*)l, 16, 0, 0);
}

// ---------------------------------------------------------------- weights
__global__ __launch_bounds__(256) void convT_k(const float* __restrict__ src,
                                               short* __restrict__ dst, int K,
                                               int N, int scale_cols,
                                               float scale) {
  int idx = blockIdx.x * 256 + threadIdx.x;
  if (idx >= N * K) return;
  int n = idx / K, k = idx % K;
  float v = src[(size_t)k * N + n];
  if (n < scale_cols) v *= scale;
  dst[idx] = f2b(v);
}

__global__ __launch_bounds__(256) void scale_bias_k(const float* __restrict__ src,
                                                    float* __restrict__ dst,
                                                    int n, int scale_cols,
                                                    float scale) {
  int i = blockIdx.x * 256 + threadIdx.x;
  if (i >= n) return;
  dst[i] = src[i] * (i < scale_cols ? scale : 1.f);
}

// Combined rel-pos bias + shift mask table: tbl[cls][h][key][query], f32.
__global__ __launch_bounds__(256) void biasmask_k(const float* __restrict__ rpb,
                                                  float* __restrict__ tbl) {
  int idx = blockIdx.x * 256 + threadIdx.x;  // < 4*12*64*64
  int q = idx & 63, key = (idx >> 6) & 63;
  int hc = idx >> 12;  // cls*12 + h
  int h = hc % 12, cls = hc / 12;
  float v;
  if (q >= 49 || key >= 49) {
    v = -1e4f;
  } else {
    int i1 = q / 7, j1 = q % 7, i2 = key / 7, j2 = key % 7;
    v = rpb[(size_t)((i1 - i2 + 6) * 13 + (j1 - j2 + 6)) * 12 + h];
    int clsh = cls >> 1, clsw = cls & 1;
    int rq = (clsh ? 1 + (i1 >= 4) : 0) * 3 + (clsw ? 1 + (j1 >= 4) : 0);
    int rk = (clsh ? 1 + (i2 >= 4) : 0) * 3 + (clsw ? 1 + (j2 >= 4) : 0);
    if (rq != rk) v -= 100.f;
  }
  tbl[idx] = v;
}

// ---------------------------------------------------------------- layernorm
template <bool GATHER>
__device__ __forceinline__ void ln_body(const float* __restrict__ x,
                                        const float* __restrict__ gw,
                                        const float* __restrict__ bw,
                                        short* __restrict__ out) {
  const int lane = threadIdx.x & 63;
  const int t = (blockIdx.x << 2) + (threadIdx.x >> 6);
  size_t srow;
  if (GATHER) {
    int bb = t / 12544, rm2 = t % 12544;
    int wi = rm2 / 49, nn = rm2 % 49;
    int wh = wi >> 4, ww = wi & 15;
    int ii = nn / 7, jj = nn % 7;
    int rr = wh * 7 + ii + 3; if (rr >= 112) rr -= 112;
    int cc = ww * 7 + jj + 3; if (cc >= 112) cc -= 112;
    srow = ((size_t)bb * 12544 + rr * 112 + cc) * 384;
  } else {
    srow = (size_t)t * 384;
  }
  const float2* src = (const float2*)(x + srow);
  const float2* g2 = (const float2*)gw;
  const float2* b2 = (const float2*)bw;
  float2 u[3];
  float s = 0.f, ss = 0.f;
#pragma unroll
  for (int k = 0; k < 3; ++k) {
    u[k] = src[lane + (k << 6)];
    s += u[k].x + u[k].y;
    ss += u[k].x * u[k].x + u[k].y * u[k].y;
  }
#pragma unroll
  for (int m = 1; m < 64; m <<= 1) {
    s += __shfl_xor(s, m, 64);
    ss += __shfl_xor(ss, m, 64);
  }
  const float mean = s * (1.f / 384.f);
  const float var = ss * (1.f / 384.f) - mean * mean;
  const float rstd = rsqrtf(var + 1e-5f);
  unsigned* o = (unsigned*)(out + (size_t)t * 384);
#pragma unroll
  for (int k = 0; k < 3; ++k) {
    int c = lane + (k << 6);
    float2 gv = g2[c], bv = b2[c];
    unsigned lo = (unsigned short)f2b((u[k].x - mean) * rstd * gv.x + bv.x);
    unsigned hi = (unsigned short)f2b((u[k].y - mean) * rstd * gv.y + bv.y);
    o[c] = lo | (hi << 16);
  }
}

__global__ __launch_bounds__(256) void ln1_k(const float* __restrict__ x,
                                             const float* __restrict__ gw,
                                             const float* __restrict__ bw,
                                             short* __restrict__ out) {
  ln_body<true>(x, gw, bw, out);
}
__global__ __launch_bounds__(256) void ln2_k(const float* __restrict__ x,
                                             const float* __restrict__ gw,
                                             const float* __restrict__ bw,
                                             short* __restrict__ out) {
  ln_body<false>(x, gw, bw, out);
}

// ---------------------------------------------------------------- GEMM
// 128x128 tile, BK=64, 4 waves (2x2), static double-buffer (64KB LDS,
// 2 blocks/CU). 32 MFMA per wave-phase (2x r4's amortization of the
// stage+drain+barrier overhead -- m233's "2-phase stall" lever).
// LDS tiles are [128 rows][8 chunks of 16B]; row stride 128B = exact
// bank wrap, so logical chunk c is stored at position c^(row&7):
//   write: gload_lds dest linear (tid*16B), global SOURCE pre-swizzled
//          chunk (tid&7)^((tid>>3)&7) (rule #21, r8-proven mechanism);
//   read:  position (4*kk+g)^(q&7) -> 2 lanes/bank = free (m136).
template <int EPI>
__device__ __forceinline__ void gemm_body(
    const short* __restrict__ A, int lda, const short* __restrict__ BT,
    int ldb, const float* __restrict__ bias, int K, short* __restrict__ outh,
    int ldo, float* __restrict__ outf, const float* __restrict__ resid) {
  __shared__ __align__(16) short A0s[8192], B0s[8192];
  __shared__ __align__(16) short A1s[8192], B1s[8192];
  const int tid = threadIdx.x;
  const int gx = gridDim.x;
  int lin = blockIdx.y * gx + blockIdx.x;
  const int cpx = (gx * gridDim.y) >> 3;
  lin = (lin & 7) * cpx + (lin >> 3);
  const int m0 = (lin / gx) << 7, n0 = (lin % gx) << 7;
  const int lane = tid & 63;
  const int wave = tid >> 6;
  const int wr = (wave >> 1) << 6, wc = (wave & 1) << 6;
  const int g = lane >> 4, q = lane & 15;
  const int q7 = q & 7;
  const int rd0 = ((g) ^ q7) << 3;        // kk=0 chunk position * 8
  const int rd1 = ((4 + g) ^ q7) << 3;    // kk=1
  const int cswz = ((tid & 7) ^ ((tid >> 3) & 7)) << 3;  // source col chunk
  const int ldst = tid << 3;              // LDS dest: linear, lane*16B

  f32x4 acc[4][4];
#pragma unroll
  for (int i = 0; i < 4; ++i)
#pragma unroll
    for (int j = 0; j < 4; ++j) acc[i][j] = (f32x4){0.f, 0.f, 0.f, 0.f};

  const short* Abase = A + (size_t)(m0 + (tid >> 3)) * lda + cswz;
  const short* Bbase = BT + (size_t)(n0 + (tid >> 3)) * ldb + cswz;

#define STAGE(kt, DA, DB)                                                     \
  do {                                                                        \
    _Pragma("unroll") for (int p = 0; p < 4; ++p) {                           \
      gload16(Abase + (size_t)(32 * p) * lda + (kt), &DA[2048 * p + ldst]);   \
      gload16(Bbase + (size_t)(32 * p) * ldb + (kt), &DB[2048 * p + ldst]);   \
    }                                                                         \
  } while (0)

#define COMPUTE(SA, SB)                                                       \
  do {                                                                        \
    _Pragma("unroll") for (int kk = 0; kk < 2; ++kk) {                        \
      const int rdo = kk ? rd1 : rd0;                                         \
      bf16x8 af[4], bfv[4];                                                   \
      _Pragma("unroll") for (int mi = 0; mi < 4; ++mi)                        \
          af[mi] = *(const bf16x8*)&SA[(wr + mi * 16 + q) * 64 + rdo];        \
      _Pragma("unroll") for (int ni = 0; ni < 4; ++ni)                        \
          bfv[ni] = *(const bf16x8*)&SB[(wc + ni * 16 + q) * 64 + rdo];       \
      _Pragma("unroll") for (int mi = 0; mi < 4; ++mi)                        \
          _Pragma("unroll") for (int ni = 0; ni < 4; ++ni)                    \
              acc[mi][ni] = mfma16(af[mi], bfv[ni], acc[mi][ni]);             \
    }                                                                         \
  } while (0)

  const int nt = K >> 6;  // 6, 12, or 24 here: even, >=6
  STAGE(0, A0s, B0s);
  __syncthreads();
  for (int t = 0; t < nt; t += 2) {
    STAGE((t + 1) << 6, A1s, B1s);
    COMPUTE(A0s, B0s);
    __syncthreads();
    if (t + 2 < nt) STAGE((t + 2) << 6, A0s, B0s);
    COMPUTE(A1s, B1s);
    __syncthreads();
  }
#undef STAGE
#undef COMPUTE

  float bv[4];
#pragma unroll
  for (int ni = 0; ni < 4; ++ni)
    bv[ni] = bias ? bias[n0 + wc + ni * 16 + q] : 0.f;

#pragma unroll
  for (int mi = 0; mi < 4; ++mi) {
#pragma unroll
    for (int r = 0; r < 4; ++r) {
      const int grow = m0 + wr + mi * 16 + g * 4 + r;
      size_t orow;
      if constexpr (EPI == 2) {
        int bb = grow / 12544, rm2 = grow % 12544;
        int wi = rm2 / 49, nn = rm2 % 49;
        int wh = wi >> 4, ww = wi & 15;
        int ii = nn / 7, jj = nn % 7;
        int rr = wh * 7 + ii + 3; if (rr >= 112) rr -= 112;
        int cc = ww * 7 + jj + 3; if (cc >= 112) cc -= 112;
        orow = ((size_t)bb * 12544 + rr * 112 + cc) * 384;
      } else {
        orow = (size_t)grow * (size_t)ldo;
      }
#pragma unroll
      for (int ni = 0; ni < 4; ++ni) {
        const int gcol = n0 + wc + ni * 16 + q;
        float v = acc[mi][ni][r] + bv[ni];
        if constexpr (EPI == 0) {
          outh[orow + gcol] = f2b(v);
        } else if constexpr (EPI == 1) {
          v = 0.5f * v * (1.f + erff(v * 0.70710678118f));
          outh[orow + gcol] = f2b(v);
        } else if constexpr (EPI == 2) {
          outf[orow + gcol] = resid[orow + gcol] + v;
        } else {
          outf[orow + gcol] += v;
        }
      }
    }
  }
}

#define GEMM_WRAP(NAME, EPI)                                                   \
  __global__ __launch_bounds__(256) void NAME(                                 \
      const short* __restrict__ A, int lda, const short* __restrict__ BT,      \
      int ldb, const float* __restrict__ bias, int K,                          \
      short* __restrict__ outh, int ldo, float* __restrict__ outf,             \
      const float* __restrict__ resid) {                                       \
    gemm_body<EPI>(A, lda, BT, ldb, bias, K, outh, ldo, outf, resid);          \
  }
GEMM_WRAP(gemm_qkv_k, 0)
GEMM_WRAP(gemm_fc1_k, 1)
GEMM_WRAP(gemm_proj_k, 2)
GEMM_WRAP(gemm_fc2_k, 3)

// ---------------------------------------------------------------- attention
// One wave per (window, head), 4 waves/block, ZERO LDS. Swapped QK^T via
// mfma_32x32x16; in-register softmax; cvt_pk + shfl_xor(32) assembles PV
// A-frags (T12); V^T B-frags straight from global; bias+mask from table.
__global__ __launch_bounds__(256) void attn_k(const short* __restrict__ qkv,
                                              const float* __restrict__ tbl,
                                              short* __restrict__ out) {
  const int lane = threadIdx.x & 63;
  const int task = blockIdx.x * 4 + (threadIdx.x >> 6);
  const int win = task / 12;
  const int h = task - win * 12;
  const int wh = (win >> 4) & 15, ww = win & 15;
  const int cls = ((wh == 15) ? 2 : 0) + ((ww == 15) ? 1 : 0);
  const int l31 = lane & 31, h5 = lane >> 5;
  const size_t tokbase = (size_t)win * 49;
  const short* base = qkv + tokbase * 1152 + h * 32;
  const bf16x8 zero8 = {0, 0, 0, 0, 0, 0, 0, 0};

  bf16x8 kf[2][2];
#pragma unroll
  for (int mi = 0; mi < 2; ++mi) {
    int row = l31 + 32 * mi;
#pragma unroll
    for (int s = 0; s < 2; ++s)
      kf[mi][s] = (row < 49)
                      ? *(const bf16x8*)(base + (size_t)row * 1152 + 384 +
                                         16 * s + 8 * h5)
                      : zero8;
  }
  bf16x8 vf[4];
#pragma unroll
  for (int kt = 0; kt < 4; ++kt) {
#pragma unroll
    for (int e = 0; e < 8; ++e) {
      int key = 16 * kt + 8 * h5 + e;
      vf[kt][e] = (key < 49) ? base[(size_t)key * 1152 + 768 + l31] : (short)0;
    }
  }

  const float* tb = tbl + ((size_t)(cls * 12 + h) << 12);

#pragma unroll
  for (int ni = 0; ni < 2; ++ni) {
    bf16x8 qf[2];
    int qrow = l31 + 32 * ni;
#pragma unroll
    for (int s = 0; s < 2; ++s)
      qf[s] = (qrow < 49)
                  ? *(const bf16x8*)(base + (size_t)qrow * 1152 + 16 * s +
                                     8 * h5)
                  : zero8;
    f32x16 st[2];
#pragma unroll
    for (int mi = 0; mi < 2; ++mi) {
      st[mi] = mfma32(kf[mi][0], qf[0], (f32x16)(0.f));
      st[mi] = mfma32(kf[mi][1], qf[1], st[mi]);
    }
#pragma unroll
    for (int mi = 0; mi < 2; ++mi)
#pragma unroll
      for (int r = 0; r < 16; ++r) {
        int koff = (r & 3) + 8 * (r >> 2) + 4 * h5;
        st[mi][r] += tb[(size_t)(32 * mi + koff) * 64 + 32 * ni + l31];
      }
    float mx = st[0][0];
#pragma unroll
    for (int r = 1; r < 16; ++r) mx = fmaxf(mx, st[0][r]);
#pragma unroll
    for (int r = 0; r < 16; ++r) mx = fmaxf(mx, st[1][r]);
    mx = fmaxf(mx, __shfl_xor(mx, 32, 64));
    float sm = 0.f;
#pragma unroll
    for (int mi = 0; mi < 2; ++mi)
#pragma unroll
      for (int r = 0; r < 16; ++r) {
        float e = __expf(st[mi][r] - mx);
        st[mi][r] = e;
        sm += e;
      }
    sm += __shfl_xor(sm, 32, 64);
    const float rinv = 1.f / sm;
#pragma unroll
    for (int mi = 0; mi < 2; ++mi)
#pragma unroll
      for (int r = 0; r < 16; ++r) st[mi][r] *= rinv;

    f32x16 acc = (f32x16)(0.f);
#pragma unroll
    for (int kt = 0; kt < 4; ++kt) {
      const int mi = kt >> 1, b8 = (kt & 1) * 8;
      unsigned q0l = cvtpk(st[mi][b8 + 0], st[mi][b8 + 1]);
      unsigned q0h = cvtpk(st[mi][b8 + 2], st[mi][b8 + 3]);
      unsigned q1l = cvtpk(st[mi][b8 + 4], st[mi][b8 + 5]);
      unsigned q1h = cvtpk(st[mi][b8 + 6], st[mi][b8 + 7]);
      unsigned sl = h5 ? q0l : q1l, sh = h5 ? q0h : q1h;
      unsigned kl = h5 ? q1l : q0l, kh = h5 ? q1h : q0h;
      unsigned rl = (unsigned)__shfl_xor((int)sl, 32, 64);
      unsigned rh = (unsigned)__shfl_xor((int)sh, 32, 64);
      u32x4 fr;
      fr[0] = h5 ? rl : kl;
      fr[1] = h5 ? rh : kh;
      fr[2] = h5 ? kl : rl;
      fr[3] = h5 ? kh : rh;
      acc = mfma32(__builtin_bit_cast(bf16x8, fr), vf[kt], acc);
    }
#pragma unroll
    for (int r = 0; r < 16; ++r) {
      int query = 32 * ni + (r & 3) + 8 * (r >> 2) + 4 * h5;
      if (ni == 0 || query < 49)
        out[(tokbase + query) * 384 + h * 32 + l31] = f2b(acc[r]);
    }
  }
}

// ---------------------------------------------------------------- launch
extern "C" void kernel_launch(void* const* d_in, const int* in_sizes, int n_in,
                              void* d_out, int out_size, void* d_ws,
                              size_t ws_size, hipStream_t stream) {
  const float* x = (const float*)d_in[0];
  const float* n1g = (const float*)d_in[1];
  const float* n1b = (const float*)d_in[2];
  const float* qkvw = (const float*)d_in[3];
  const float* qkvb = (const float*)d_in[4];
  const float* projw = (const float*)d_in[5];
  const float* projb = (const float*)d_in[6];
  const float* rpb = (const float*)d_in[7];
  const float* n2g = (const float*)d_in[8];
  const float* n2b = (const float*)d_in[9];
  const float* fc1w = (const float*)d_in[10];
  const float* fc1b = (const float*)d_in[11];
  const float* fc2w = (const float*)d_in[12];
  const float* fc2b = (const float*)d_in[13];
  float* out = (float*)d_out;

  char* ws = (char*)d_ws;
  short* w_qkvT = (short*)(ws + 0);            // 884736 B
  short* w_projT = (short*)(ws + 884736);      // 294912 B
  short* w_fc1T = (short*)(ws + 1179648);      // 1179648 B
  short* w_fc2T = (short*)(ws + 2359296);      // 1179648 B
  float* w_qb = (float*)(ws + 3538944);        // 4608 B
  float* tbl = (float*)(ws + 3543552);         // 786432 B
  const size_t o_qkv = 4329984;
  short* qkvbuf = (short*)(ws + o_qkv);        // 462422016 B
  const size_t o_hwin = o_qkv + 462422016ull;
  short* hwin = (short*)(ws + o_hwin);         // 154140672 B
  const size_t o_fc1 = o_hwin + 154140672ull;

  int NC;
  size_t fc1_off = o_fc1;
  if (ws_size >= o_fc1 + 616562688ull) NC = 1;
  else if (ws_size >= o_fc1 + 308281344ull) NC = 2;
  else if (ws_size >= o_fc1 + 154140672ull) NC = 4;
  else { NC = 4; fc1_off = o_hwin; }
  short* fc1c = (short*)(ws + fc1_off);
  short* h2 = qkvbuf;

  const float qscale = 0.17677669529663687f;

  convT_k<<<(442368 + 255) / 256, 256, 0, stream>>>(qkvw, w_qkvT, 384, 1152, 384, qscale);
  convT_k<<<(147456 + 255) / 256, 256, 0, stream>>>(projw, w_projT, 384, 384, 0, 1.f);
  convT_k<<<(589824 + 255) / 256, 256, 0, stream>>>(fc1w, w_fc1T, 384, 1536, 0, 1.f);
  convT_k<<<(589824 + 255) / 256, 256, 0, stream>>>(fc2w, w_fc2T, 1536, 384, 0, 1.f);
  scale_bias_k<<<5, 256, 0, stream>>>(qkvb, w_qb, 1152, 384, qscale);
  biasmask_k<<<768, 256, 0, stream>>>(rpb, tbl);

  ln1_k<<<50176, 256, 0, stream>>>(x, n1g, n1b, hwin);
  gemm_qkv_k<<<dim3(9, 1568), 256, 0, stream>>>(hwin, 384, w_qkvT, 384, w_qb,
                                                384, qkvbuf, 1152, nullptr,
                                                nullptr);
  attn_k<<<12288, 256, 0, stream>>>(qkvbuf, tbl, hwin);
  gemm_proj_k<<<dim3(3, 1568), 256, 0, stream>>>(hwin, 384, w_projT, 384,
                                                 projb, 384, nullptr, 384, out,
                                                 x);
  ln2_k<<<50176, 256, 0, stream>>>(out, n2g, n2b, h2);
  const int CK = 1536 / NC;
  for (int c = 0; c < NC; ++c) {
    gemm_fc1_k<<<dim3(CK >> 7, 1568), 256, 0, stream>>>(
        h2, 384, w_fc1T + (size_t)c * CK * 384, 384, fc1b + c * CK, 384, fc1c,
        CK, nullptr, nullptr);
    gemm_fc2_k<<<dim3(3, 1568), 256, 0, stream>>>(
        fc1c, CK, w_fc2T + c * CK, 1536, (c == 0) ? fc2b : nullptr, CK,
        nullptr, 384, out, nullptr);
  }
}

// Round 10
// 2099.613 us; speedup vs baseline: 1.2904x; 1.0135x over previous
//
#include <hip/hip_runtime.h>
#include <hip/hip_bf16.h>

typedef short bf16x8 __attribute__((ext_vector_type(8)));
typedef float f32x4 __attribute__((ext_vector_type(4)));
typedef float f32x16 __attribute__((ext_vector_type(16)));
typedef unsigned int u32x4 __attribute__((ext_vector_type(4)));

typedef __attribute__((address_space(1))) void gvoid;
typedef __attribute__((address_space(3))) void lvoid;

__device__ __forceinline__ short f2b(float f) {
  __hip_bfloat16 h = __float2bfloat16(f);
  return __builtin_bit_cast(short, h);
}

__device__ __forceinline__ f32x4 mfma16(bf16x8 a, bf16x8 b, f32x4 c) {
  return __builtin_amdgcn_mfma_f32_16x16x32_bf16(a, b, c, 0, 0, 0);
}

__device__ __forceinline__ f32x16 mfma32(bf16x8 a, bf16x8 b, f32x16 c) {
  return __builtin_amdgcn_mfma_f32_32x32x16_bf16(a, b, c, 0, 0, 0);
}

__device__ __forceinline__ unsigned cvtpk(float lo, float hi) {
  unsigned r;
  asm("v_cvt_pk_bf16_f32 %0, %1, %2" : "=v"(r) : "v"(lo), "v"(hi));
  return r;
}

__device__ __forceinline__ void gload16(const void* g, void* l) {
  __builtin_amdgcn_global_load_lds((const gvoid*)g, (lvoid*)l, 16, 0, 0);
}

// ---------------------------------------------------------------- weights
__global__ __launch_bounds__(256) void convT_k(const float* __restrict__ src,
                                               short* __restrict__ dst, int K,
                                               int N, int scale_cols,
                                               float scale) {
  int idx = blockIdx.x * 256 + threadIdx.x;
  if (idx >= N * K) return;
  int n = idx / K, k = idx % K;
  float v = src[(size_t)k * N + n];
  if (n < scale_cols) v *= scale;
  dst[idx] = f2b(v);
}

__global__ __launch_bounds__(256) void scale_bias_k(const float* __restrict__ src,
                                                    float* __restrict__ dst,
                                                    int n, int scale_cols,
                                                    float scale) {
  int i = blockIdx.x * 256 + threadIdx.x;
  if (i >= n) return;
  dst[i] = src[i] * (i < scale_cols ? scale : 1.f);
}

// Combined rel-pos bias + shift mask table: tbl[cls][h][key][query], f32.
__global__ __launch_bounds__(256) void biasmask_k(const float* __restrict__ rpb,
                                                  float* __restrict__ tbl) {
  int idx = blockIdx.x * 256 + threadIdx.x;  // < 4*12*64*64
  int q = idx & 63, key = (idx >> 6) & 63;
  int hc = idx >> 12;  // cls*12 + h
  int h = hc % 12, cls = hc / 12;
  float v;
  if (q >= 49 || key >= 49) {
    v = -1e4f;
  } else {
    int i1 = q / 7, j1 = q % 7, i2 = key / 7, j2 = key % 7;
    v = rpb[(size_t)((i1 - i2 + 6) * 13 + (j1 - j2 + 6)) * 12 + h];
    int clsh = cls >> 1, clsw = cls & 1;
    int rq = (clsh ? 1 + (i1 >= 4) : 0) * 3 + (clsw ? 1 + (j1 >= 4) : 0);
    int rk = (clsh ? 1 + (i2 >= 4) : 0) * 3 + (clsw ? 1 + (j2 >= 4) : 0);
    if (rq != rk) v -= 100.f;
  }
  tbl[idx] = v;
}

// ---------------------------------------------------------------- layernorm
template <bool GATHER>
__device__ __forceinline__ void ln_body(const float* __restrict__ x,
                                        const float* __restrict__ gw,
                                        const float* __restrict__ bw,
                                        short* __restrict__ out) {
  const int lane = threadIdx.x & 63;
  const int t = (blockIdx.x << 2) + (threadIdx.x >> 6);
  size_t srow;
  if (GATHER) {
    int bb = t / 12544, rm2 = t % 12544;
    int wi = rm2 / 49, nn = rm2 % 49;
    int wh = wi >> 4, ww = wi & 15;
    int ii = nn / 7, jj = nn % 7;
    int rr = wh * 7 + ii + 3; if (rr >= 112) rr -= 112;
    int cc = ww * 7 + jj + 3; if (cc >= 112) cc -= 112;
    srow = ((size_t)bb * 12544 + rr * 112 + cc) * 384;
  } else {
    srow = (size_t)t * 384;
  }
  const float2* src = (const float2*)(x + srow);
  const float2* g2 = (const float2*)gw;
  const float2* b2 = (const float2*)bw;
  float2 u[3];
  float s = 0.f, ss = 0.f;
#pragma unroll
  for (int k = 0; k < 3; ++k) {
    u[k] = src[lane + (k << 6)];
    s += u[k].x + u[k].y;
    ss += u[k].x * u[k].x + u[k].y * u[k].y;
  }
#pragma unroll
  for (int m = 1; m < 64; m <<= 1) {
    s += __shfl_xor(s, m, 64);
    ss += __shfl_xor(ss, m, 64);
  }
  const float mean = s * (1.f / 384.f);
  const float var = ss * (1.f / 384.f) - mean * mean;
  const float rstd = rsqrtf(var + 1e-5f);
  unsigned* o = (unsigned*)(out + (size_t)t * 384);
#pragma unroll
  for (int k = 0; k < 3; ++k) {
    int c = lane + (k << 6);
    float2 gv = g2[c], bv = b2[c];
    unsigned lo = (unsigned short)f2b((u[k].x - mean) * rstd * gv.x + bv.x);
    unsigned hi = (unsigned short)f2b((u[k].y - mean) * rstd * gv.y + bv.y);
    o[c] = lo | (hi << 16);
  }
}

__global__ __launch_bounds__(256) void ln1_k(const float* __restrict__ x,
                                             const float* __restrict__ gw,
                                             const float* __restrict__ bw,
                                             short* __restrict__ out) {
  ln_body<true>(x, gw, bw, out);
}
__global__ __launch_bounds__(256) void ln2_k(const float* __restrict__ x,
                                             const float* __restrict__ gw,
                                             const float* __restrict__ bw,
                                             short* __restrict__ out) {
  ln_body<false>(x, gw, bw, out);
}

// ---------------------------------------------------------------- GEMM
// 128x128 tile, BK=64, 4 waves (2x2), static dbuf (64KB LDS, 2 blk/CU),
// r9 geometry + swizzle (conflicts=0). NEW: m201-style 4-sub-phase
// schedule per K-tile -- per phase {ds_read frag subset || issue 2
// gload_lds -> barrier -> setprio(1) 8xMFMA setprio(0) -> barrier};
// counted vmcnt(2) only at tile boundary (t+2's 2 loads stay in
// flight), vmcnt(0) only at tail (T3+T4; m218 counted-vs-drain0).
// ph4 stages tile t+2 into CUR buffer (all cur reads barrier-complete
// after ph3); sched_barrier(0) pins it against hoisting (rule #18).
template <int EPI>
__device__ __forceinline__ void gemm_body(
    const short* __restrict__ A, int lda, const short* __restrict__ BT,
    int ldb, const float* __restrict__ bias, int K, short* __restrict__ outh,
    int ldo, float* __restrict__ outf, const float* __restrict__ resid) {
  __shared__ __align__(16) short A0s[8192], B0s[8192];
  __shared__ __align__(16) short A1s[8192], B1s[8192];
  const int tid = threadIdx.x;
  const int gx = gridDim.x;
  int lin = blockIdx.y * gx + blockIdx.x;
  const int cpx = (gx * gridDim.y) >> 3;
  lin = (lin & 7) * cpx + (lin >> 3);
  const int m0 = (lin / gx) << 7, n0 = (lin % gx) << 7;
  const int lane = tid & 63;
  const int wave = tid >> 6;
  const int wr = (wave >> 1) << 6, wc = (wave & 1) << 6;
  const int g = lane >> 4, q = lane & 15;
  const int q7 = q & 7;
  const int rd0 = ((g) ^ q7) << 3;
  const int rd1 = ((4 + g) ^ q7) << 3;
  const int cswz = ((tid & 7) ^ ((tid >> 3) & 7)) << 3;
  const int ldst = tid << 3;

  f32x4 acc[4][4];
#pragma unroll
  for (int i = 0; i < 4; ++i)
#pragma unroll
    for (int j = 0; j < 4; ++j) acc[i][j] = (f32x4){0.f, 0.f, 0.f, 0.f};

  const short* Abase = A + (size_t)(m0 + (tid >> 3)) * lda + cswz;
  const short* Bbase = BT + (size_t)(n0 + (tid >> 3)) * ldb + cswz;

#define SA01(kt, DA)                                            \
  do {                                                          \
    gload16(Abase + (kt), &DA[ldst]);                           \
    gload16(Abase + (size_t)32 * lda + (kt), &DA[2048 + ldst]); \
  } while (0)
#define SA23(kt, DA)                                            \
  do {                                                          \
    gload16(Abase + (size_t)64 * lda + (kt), &DA[4096 + ldst]); \
    gload16(Abase + (size_t)96 * lda + (kt), &DA[6144 + ldst]); \
  } while (0)
#define SB01(kt, DB)                                            \
  do {                                                          \
    gload16(Bbase + (kt), &DB[ldst]);                           \
    gload16(Bbase + (size_t)32 * ldb + (kt), &DB[2048 + ldst]); \
  } while (0)
#define SB23(kt, DB)                                            \
  do {                                                          \
    gload16(Bbase + (size_t)64 * ldb + (kt), &DB[4096 + ldst]); \
    gload16(Bbase + (size_t)96 * ldb + (kt), &DB[6144 + ldst]); \
  } while (0)

#define READ_AF(i, SA)                                               \
  do {                                                               \
    af[i][0] = *(const bf16x8*)&SA[(wr + (i)*16 + q) * 64 + rd0];    \
    af[i][1] = *(const bf16x8*)&SA[(wr + (i)*16 + q) * 64 + rd1];    \
  } while (0)
#define READ_BF(i, SB)                                               \
  do {                                                               \
    bfr[i][0] = *(const bf16x8*)&SB[(wc + (i)*16 + q) * 64 + rd0];   \
    bfr[i][1] = *(const bf16x8*)&SB[(wc + (i)*16 + q) * 64 + rd1];   \
  } while (0)

#define QUAD(a, b)                                                       \
  do {                                                                   \
    __builtin_amdgcn_s_setprio(1);                                       \
    _Pragma("unroll") for (int ks = 0; ks < 2; ++ks)                     \
        _Pragma("unroll") for (int i = 0; i < 2; ++i)                    \
            _Pragma("unroll") for (int j = 0; j < 2; ++j)                \
                acc[2 * (a) + i][2 * (b) + j] = mfma16(                  \
                    af[2 * (a) + i][ks], bfr[2 * (b) + j][ks],           \
                    acc[2 * (a) + i][2 * (b) + j]);                      \
    __builtin_amdgcn_s_setprio(0);                                       \
  } while (0)

#define VMW2                                          \
  do {                                                \
    asm volatile("s_waitcnt vmcnt(2)" ::: "memory");  \
    __builtin_amdgcn_sched_barrier(0);                \
  } while (0)
#define VMW0                                          \
  do {                                                \
    asm volatile("s_waitcnt vmcnt(0)" ::: "memory");  \
    __builtin_amdgcn_sched_barrier(0);                \
  } while (0)
#define BAR __builtin_amdgcn_s_barrier()

#define TILE(t, SA, SB, NA, NB)                              \
  do {                                                       \
    READ_AF(0, SA); READ_AF(1, SA);                          \
    READ_BF(0, SB); READ_BF(1, SB);                          \
    if ((t) + 1 < nt) SA23(((t) + 1) << 6, NA);              \
    BAR; QUAD(0, 0); BAR;                                    \
    READ_BF(2, SB); READ_BF(3, SB);                          \
    if ((t) + 1 < nt) SB01(((t) + 1) << 6, NB);              \
    BAR; QUAD(0, 1); BAR;                                    \
    READ_AF(2, SA); READ_AF(3, SA);                          \
    if ((t) + 1 < nt) SB23(((t) + 1) << 6, NB);              \
    BAR; QUAD(1, 0); BAR;                                    \
    __builtin_amdgcn_sched_barrier(0);                       \
    if ((t) + 2 < nt) SA01(((t) + 2) << 6, SA);              \
    QUAD(1, 1);                                              \
    if ((t) + 1 < nt) {                                      \
      if ((t) + 2 < nt) VMW2; else VMW0;                     \
    }                                                        \
    BAR;                                                     \
  } while (0)

  bf16x8 af[4][2], bfr[4][2];
  const int nt = K >> 6;  // 6, 12, or 24: even, >=6

  // prologue: tile 0 fully (8 loads) + tile 1's SA01 (2 loads)
  SA01(0, A0s); SA23(0, A0s); SB01(0, B0s); SB23(0, B0s);
  SA01(64, A1s);
  VMW2;  // tile 0 landed (oldest 8 of 10)
  BAR;

  for (int t = 0; t < nt; t += 2) {
    TILE(t, A0s, B0s, A1s, B1s);
    TILE(t + 1, A1s, B1s, A0s, B0s);
  }
#undef SA01
#undef SA23
#undef SB01
#undef SB23
#undef READ_AF
#undef READ_BF
#undef QUAD
#undef VMW2
#undef VMW0
#undef BAR
#undef TILE

  float bv[4];
#pragma unroll
  for (int ni = 0; ni < 4; ++ni)
    bv[ni] = bias ? bias[n0 + wc + ni * 16 + q] : 0.f;

#pragma unroll
  for (int mi = 0; mi < 4; ++mi) {
#pragma unroll
    for (int r = 0; r < 4; ++r) {
      const int grow = m0 + wr + mi * 16 + g * 4 + r;
      size_t orow;
      if constexpr (EPI == 2) {
        int bb = grow / 12544, rm2 = grow % 12544;
        int wi = rm2 / 49, nn = rm2 % 49;
        int wh = wi >> 4, ww = wi & 15;
        int ii = nn / 7, jj = nn % 7;
        int rr = wh * 7 + ii + 3; if (rr >= 112) rr -= 112;
        int cc = ww * 7 + jj + 3; if (cc >= 112) cc -= 112;
        orow = ((size_t)bb * 12544 + rr * 112 + cc) * 384;
      } else {
        orow = (size_t)grow * (size_t)ldo;
      }
#pragma unroll
      for (int ni = 0; ni < 4; ++ni) {
        const int gcol = n0 + wc + ni * 16 + q;
        float v = acc[mi][ni][r] + bv[ni];
        if constexpr (EPI == 0) {
          outh[orow + gcol] = f2b(v);
        } else if constexpr (EPI == 1) {
          v = 0.5f * v * (1.f + erff(v * 0.70710678118f));
          outh[orow + gcol] = f2b(v);
        } else if constexpr (EPI == 2) {
          outf[orow + gcol] = resid[orow + gcol] + v;
        } else {
          outf[orow + gcol] += v;
        }
      }
    }
  }
}

#define GEMM_WRAP(NAME, EPI)                                                   \
  __global__ __launch_bounds__(256) void NAME(                                 \
      const short* __restrict__ A, int lda, const short* __restrict__ BT,      \
      int ldb, const float* __restrict__ bias, int K,                          \
      short* __restrict__ outh, int ldo, float* __restrict__ outf,             \
      const float* __restrict__ resid) {                                       \
    gemm_body<EPI>(A, lda, BT, ldb, bias, K, outh, ldo, outf, resid);          \
  }
GEMM_WRAP(gemm_qkv_k, 0)
GEMM_WRAP(gemm_fc1_k, 1)
GEMM_WRAP(gemm_proj_k, 2)
GEMM_WRAP(gemm_fc2_k, 3)

// ---------------------------------------------------------------- attention
// One wave per (window, head), 4 waves/block, ZERO LDS. Swapped QK^T via
// mfma_32x32x16; in-register softmax; cvt_pk + shfl_xor(32) assembles PV
// A-frags (T12); V^T B-frags straight from global; bias+mask from table.
__global__ __launch_bounds__(256) void attn_k(const short* __restrict__ qkv,
                                              const float* __restrict__ tbl,
                                              short* __restrict__ out) {
  const int lane = threadIdx.x & 63;
  const int task = blockIdx.x * 4 + (threadIdx.x >> 6);
  const int win = task / 12;
  const int h = task - win * 12;
  const int wh = (win >> 4) & 15, ww = win & 15;
  const int cls = ((wh == 15) ? 2 : 0) + ((ww == 15) ? 1 : 0);
  const int l31 = lane & 31, h5 = lane >> 5;
  const size_t tokbase = (size_t)win * 49;
  const short* base = qkv + tokbase * 1152 + h * 32;
  const bf16x8 zero8 = {0, 0, 0, 0, 0, 0, 0, 0};

  bf16x8 kf[2][2];
#pragma unroll
  for (int mi = 0; mi < 2; ++mi) {
    int row = l31 + 32 * mi;
#pragma unroll
    for (int s = 0; s < 2; ++s)
      kf[mi][s] = (row < 49)
                      ? *(const bf16x8*)(base + (size_t)row * 1152 + 384 +
                                         16 * s + 8 * h5)
                      : zero8;
  }
  bf16x8 vf[4];
#pragma unroll
  for (int kt = 0; kt < 4; ++kt) {
#pragma unroll
    for (int e = 0; e < 8; ++e) {
      int key = 16 * kt + 8 * h5 + e;
      vf[kt][e] = (key < 49) ? base[(size_t)key * 1152 + 768 + l31] : (short)0;
    }
  }

  const float* tb = tbl + ((size_t)(cls * 12 + h) << 12);

#pragma unroll
  for (int ni = 0; ni < 2; ++ni) {
    bf16x8 qf[2];
    int qrow = l31 + 32 * ni;
#pragma unroll
    for (int s = 0; s < 2; ++s)
      qf[s] = (qrow < 49)
                  ? *(const bf16x8*)(base + (size_t)qrow * 1152 + 16 * s +
                                     8 * h5)
                  : zero8;
    f32x16 st[2];
#pragma unroll
    for (int mi = 0; mi < 2; ++mi) {
      st[mi] = mfma32(kf[mi][0], qf[0], (f32x16)(0.f));
      st[mi] = mfma32(kf[mi][1], qf[1], st[mi]);
    }
#pragma unroll
    for (int mi = 0; mi < 2; ++mi)
#pragma unroll
      for (int r = 0; r < 16; ++r) {
        int koff = (r & 3) + 8 * (r >> 2) + 4 * h5;
        st[mi][r] += tb[(size_t)(32 * mi + koff) * 64 + 32 * ni + l31];
      }
    float mx = st[0][0];
#pragma unroll
    for (int r = 1; r < 16; ++r) mx = fmaxf(mx, st[0][r]);
#pragma unroll
    for (int r = 0; r < 16; ++r) mx = fmaxf(mx, st[1][r]);
    mx = fmaxf(mx, __shfl_xor(mx, 32, 64));
    float sm = 0.f;
#pragma unroll
    for (int mi = 0; mi < 2; ++mi)
#pragma unroll
      for (int r = 0; r < 16; ++r) {
        float e = __expf(st[mi][r] - mx);
        st[mi][r] = e;
        sm += e;
      }
    sm += __shfl_xor(sm, 32, 64);
    const float rinv = 1.f / sm;
#pragma unroll
    for (int mi = 0; mi < 2; ++mi)
#pragma unroll
      for (int r = 0; r < 16; ++r) st[mi][r] *= rinv;

    f32x16 acc = (f32x16)(0.f);
#pragma unroll
    for (int kt = 0; kt < 4; ++kt) {
      const int mi = kt >> 1, b8 = (kt & 1) * 8;
      unsigned q0l = cvtpk(st[mi][b8 + 0], st[mi][b8 + 1]);
      unsigned q0h = cvtpk(st[mi][b8 + 2], st[mi][b8 + 3]);
      unsigned q1l = cvtpk(st[mi][b8 + 4], st[mi][b8 + 5]);
      unsigned q1h = cvtpk(st[mi][b8 + 6], st[mi][b8 + 7]);
      unsigned sl = h5 ? q0l : q1l, sh = h5 ? q0h : q1h;
      unsigned kl = h5 ? q1l : q0l, kh = h5 ? q1h : q0h;
      unsigned rl = (unsigned)__shfl_xor((int)sl, 32, 64);
      unsigned rh = (unsigned)__shfl_xor((int)sh, 32, 64);
      u32x4 fr;
      fr[0] = h5 ? rl : kl;
      fr[1] = h5 ? rh : kh;
      fr[2] = h5 ? kl : rl;
      fr[3] = h5 ? kh : rh;
      acc = mfma32(__builtin_bit_cast(bf16x8, fr), vf[kt], acc);
    }
#pragma unroll
    for (int r = 0; r < 16; ++r) {
      int query = 32 * ni + (r & 3) + 8 * (r >> 2) + 4 * h5;
      if (ni == 0 || query < 49)
        out[(tokbase + query) * 384 + h * 32 + l31] = f2b(acc[r]);
    }
  }
}

// ---------------------------------------------------------------- launch
extern "C" void kernel_launch(void* const* d_in, const int* in_sizes, int n_in,
                              void* d_out, int out_size, void* d_ws,
                              size_t ws_size, hipStream_t stream) {
  const float* x = (const float*)d_in[0];
  const float* n1g = (const float*)d_in[1];
  const float* n1b = (const float*)d_in[2];
  const float* qkvw = (const float*)d_in[3];
  const float* qkvb = (const float*)d_in[4];
  const float* projw = (const float*)d_in[5];
  const float* projb = (const float*)d_in[6];
  const float* rpb = (const float*)d_in[7];
  const float* n2g = (const float*)d_in[8];
  const float* n2b = (const float*)d_in[9];
  const float* fc1w = (const float*)d_in[10];
  const float* fc1b = (const float*)d_in[11];
  const float* fc2w = (const float*)d_in[12];
  const float* fc2b = (const float*)d_in[13];
  float* out = (float*)d_out;

  char* ws = (char*)d_ws;
  short* w_qkvT = (short*)(ws + 0);            // 884736 B
  short* w_projT = (short*)(ws + 884736);      // 294912 B
  short* w_fc1T = (short*)(ws + 1179648);      // 1179648 B
  short* w_fc2T = (short*)(ws + 2359296);      // 1179648 B
  float* w_qb = (float*)(ws + 3538944);        // 4608 B
  float* tbl = (float*)(ws + 3543552);         // 786432 B
  const size_t o_qkv = 4329984;
  short* qkvbuf = (short*)(ws + o_qkv);        // 462422016 B
  const size_t o_hwin = o_qkv + 462422016ull;
  short* hwin = (short*)(ws + o_hwin);         // 154140672 B
  const size_t o_fc1 = o_hwin + 154140672ull;

  int NC;
  size_t fc1_off = o_fc1;
  if (ws_size >= o_fc1 + 616562688ull) NC = 1;
  else if (ws_size >= o_fc1 + 308281344ull) NC = 2;
  else if (ws_size >= o_fc1 + 154140672ull) NC = 4;
  else { NC = 4; fc1_off = o_hwin; }
  short* fc1c = (short*)(ws + fc1_off);
  short* h2 = qkvbuf;

  const float qscale = 0.17677669529663687f;

  convT_k<<<(442368 + 255) / 256, 256, 0, stream>>>(qkvw, w_qkvT, 384, 1152, 384, qscale);
  convT_k<<<(147456 + 255) / 256, 256, 0, stream>>>(projw, w_projT, 384, 384, 0, 1.f);
  convT_k<<<(589824 + 255) / 256, 256, 0, stream>>>(fc1w, w_fc1T, 384, 1536, 0, 1.f);
  convT_k<<<(589824 + 255) / 256, 256, 0, stream>>>(fc2w, w_fc2T, 1536, 384, 0, 1.f);
  scale_bias_k<<<5, 256, 0, stream>>>(qkvb, w_qb, 1152, 384, qscale);
  biasmask_k<<<768, 256, 0, stream>>>(rpb, tbl);

  ln1_k<<<50176, 256, 0, stream>>>(x, n1g, n1b, hwin);
  gemm_qkv_k<<<dim3(9, 1568), 256, 0, stream>>>(hwin, 384, w_qkvT, 384, w_qb,
                                                384, qkvbuf, 1152, nullptr,
                                                nullptr);
  attn_k<<<12288, 256, 0, stream>>>(qkvbuf, tbl, hwin);
  gemm_proj_k<<<dim3(3, 1568), 256, 0, stream>>>(hwin, 384, w_projT, 384,
                                                 projb, 384, nullptr, 384, out,
                                                 x);
  ln2_k<<<50176, 256, 0, stream>>>(out, n2g, n2b, h2);
  const int CK = 1536 / NC;
  for (int c = 0; c < NC; ++c) {
    gemm_fc1_k<<<dim3(CK >> 7, 1568), 256, 0, stream>>>(
        h2, 384, w_fc1T + (size_t)c * CK * 384, 384, fc1b + c * CK, 384, fc1c,
        CK, nullptr, nullptr);
    gemm_fc2_k<<<dim3(3, 1568), 256, 0, stream>>>(
        fc1c, CK, w_fc2T + c * CK, 1536, (c == 0) ? fc2b : nullptr, CK,
        nullptr, 384, out, nullptr);
  }
}

// Round 11
// 1929.412 us; speedup vs baseline: 1.4043x; 1.0882x over previous
//
#include <hip/hip_runtime.h>
#include <hip/hip_bf16.h>

typedef short bf16x8 __attribute__((ext_vector_type(8)));
typedef float f32x4 __attribute__((ext_vector_type(4)));
typedef float f32x16 __attribute__((ext_vector_type(16)));
typedef unsigned int u32x4 __attribute__((ext_vector_type(4)));
typedef unsigned int u32x2 __attribute__((ext_vector_type(2)));

typedef __attribute__((address_space(1))) void gvoid;
typedef __attribute__((address_space(3))) void lvoid;

__device__ __forceinline__ short f2b(float f) {
  __hip_bfloat16 h = __float2bfloat16(f);
  return __builtin_bit_cast(short, h);
}

__device__ __forceinline__ f32x4 mfma16(bf16x8 a, bf16x8 b, f32x4 c) {
  return __builtin_amdgcn_mfma_f32_16x16x32_bf16(a, b, c, 0, 0, 0);
}

__device__ __forceinline__ f32x16 mfma32(bf16x8 a, bf16x8 b, f32x16 c) {
  return __builtin_amdgcn_mfma_f32_32x32x16_bf16(a, b, c, 0, 0, 0);
}

__device__ __forceinline__ unsigned cvtpk(float lo, float hi) {
  unsigned r;
  asm("v_cvt_pk_bf16_f32 %0, %1, %2" : "=v"(r) : "v"(lo), "v"(hi));
  return r;
}

__device__ __forceinline__ void gload16(const void* g, void* l) {
  __builtin_amdgcn_global_load_lds((const gvoid*)g, (lvoid*)l, 16, 0, 0);
}

// ---------------------------------------------------------------- weights
__global__ __launch_bounds__(256) void convT_k(const float* __restrict__ src,
                                               short* __restrict__ dst, int K,
                                               int N, int scale_cols,
                                               float scale) {
  int idx = blockIdx.x * 256 + threadIdx.x;
  if (idx >= N * K) return;
  int n = idx / K, k = idx % K;
  float v = src[(size_t)k * N + n];
  if (n < scale_cols) v *= scale;
  dst[idx] = f2b(v);
}

__global__ __launch_bounds__(256) void scale_bias_k(const float* __restrict__ src,
                                                    float* __restrict__ dst,
                                                    int n, int scale_cols,
                                                    float scale) {
  int i = blockIdx.x * 256 + threadIdx.x;
  if (i >= n) return;
  dst[i] = src[i] * (i < scale_cols ? scale : 1.f);
}

// Combined rel-pos bias + shift mask table: tbl[cls][h][key][query], f32.
__global__ __launch_bounds__(256) void biasmask_k(const float* __restrict__ rpb,
                                                  float* __restrict__ tbl) {
  int idx = blockIdx.x * 256 + threadIdx.x;  // < 4*12*64*64
  int q = idx & 63, key = (idx >> 6) & 63;
  int hc = idx >> 12;  // cls*12 + h
  int h = hc % 12, cls = hc / 12;
  float v;
  if (q >= 49 || key >= 49) {
    v = -1e4f;
  } else {
    int i1 = q / 7, j1 = q % 7, i2 = key / 7, j2 = key % 7;
    v = rpb[(size_t)((i1 - i2 + 6) * 13 + (j1 - j2 + 6)) * 12 + h];
    int clsh = cls >> 1, clsw = cls & 1;
    int rq = (clsh ? 1 + (i1 >= 4) : 0) * 3 + (clsw ? 1 + (j1 >= 4) : 0);
    int rk = (clsh ? 1 + (i2 >= 4) : 0) * 3 + (clsw ? 1 + (j2 >= 4) : 0);
    if (rq != rk) v -= 100.f;
  }
  tbl[idx] = v;
}

// ---------------------------------------------------------------- layernorm
template <bool GATHER>
__device__ __forceinline__ void ln_body(const float* __restrict__ x,
                                        const float* __restrict__ gw,
                                        const float* __restrict__ bw,
                                        short* __restrict__ out) {
  const int lane = threadIdx.x & 63;
  const int t = (blockIdx.x << 2) + (threadIdx.x >> 6);
  size_t srow;
  if (GATHER) {
    int bb = t / 12544, rm2 = t % 12544;
    int wi = rm2 / 49, nn = rm2 % 49;
    int wh = wi >> 4, ww = wi & 15;
    int ii = nn / 7, jj = nn % 7;
    int rr = wh * 7 + ii + 3; if (rr >= 112) rr -= 112;
    int cc = ww * 7 + jj + 3; if (cc >= 112) cc -= 112;
    srow = ((size_t)bb * 12544 + rr * 112 + cc) * 384;
  } else {
    srow = (size_t)t * 384;
  }
  const float2* src = (const float2*)(x + srow);
  const float2* g2 = (const float2*)gw;
  const float2* b2 = (const float2*)bw;
  float2 u[3];
  float s = 0.f, ss = 0.f;
#pragma unroll
  for (int k = 0; k < 3; ++k) {
    u[k] = src[lane + (k << 6)];
    s += u[k].x + u[k].y;
    ss += u[k].x * u[k].x + u[k].y * u[k].y;
  }
#pragma unroll
  for (int m = 1; m < 64; m <<= 1) {
    s += __shfl_xor(s, m, 64);
    ss += __shfl_xor(ss, m, 64);
  }
  const float mean = s * (1.f / 384.f);
  const float var = ss * (1.f / 384.f) - mean * mean;
  const float rstd = rsqrtf(var + 1e-5f);
  unsigned* o = (unsigned*)(out + (size_t)t * 384);
#pragma unroll
  for (int k = 0; k < 3; ++k) {
    int c = lane + (k << 6);
    float2 gv = g2[c], bv = b2[c];
    unsigned lo = (unsigned short)f2b((u[k].x - mean) * rstd * gv.x + bv.x);
    unsigned hi = (unsigned short)f2b((u[k].y - mean) * rstd * gv.y + bv.y);
    o[c] = lo | (hi << 16);
  }
}

__global__ __launch_bounds__(256) void ln1_k(const float* __restrict__ x,
                                             const float* __restrict__ gw,
                                             const float* __restrict__ bw,
                                             short* __restrict__ out) {
  ln_body<true>(x, gw, bw, out);
}
__global__ __launch_bounds__(256) void ln2_k(const float* __restrict__ x,
                                             const float* __restrict__ gw,
                                             const float* __restrict__ bw,
                                             short* __restrict__ out) {
  ln_body<false>(x, gw, bw, out);
}

// ---------------------------------------------------------------- GEMM
// 128x128 tile, BK=64, **512 threads / 8 waves** (2x4 wave grid, wave
// tile 64x32) -- doubles occupancy to 16 waves/CU (4/SIMD) at the same
// 64KB LDS (the r4-r10 plateau ran 2 waves/SIMD; latency-hiding was the
// invariant bottleneck). Static dbuf + __syncthreads (r9-best), r9
// swizzle (conflicts=0): source chunk (tid&7)^(row&7), read chunk
// (4kk+g)^(q&7). SWAPPED operand mfma16(bfv, af): D[n-quad][m] -> each
// reg-quad = 4 consecutive n -> 8 vector stores (8B/16B) per thread
// instead of 64 scalar 2B stores.
template <int EPI>
__device__ __forceinline__ void gemm_body(
    const short* __restrict__ A, int lda, const short* __restrict__ BT,
    int ldb, const float* __restrict__ bias, int K, short* __restrict__ outh,
    int ldo, float* __restrict__ outf, const float* __restrict__ resid) {
  __shared__ __align__(16) short A0s[8192], B0s[8192];
  __shared__ __align__(16) short A1s[8192], B1s[8192];
  const int tid = threadIdx.x;
  const int gx = gridDim.x;
  int lin = blockIdx.y * gx + blockIdx.x;
  const int cpx = (gx * gridDim.y) >> 3;
  lin = (lin & 7) * cpx + (lin >> 3);
  const int m0 = (lin / gx) << 7, n0 = (lin % gx) << 7;
  const int lane = tid & 63;
  const int wave = tid >> 6;           // 0..7
  const int wr = (wave >> 2) << 6;     // 0 or 64
  const int wc = (wave & 3) << 5;      // 0,32,64,96
  const int g = lane >> 4, q = lane & 15;
  const int q7 = q & 7;
  const int rd0 = ((g) ^ q7) << 3;     // kk=0 chunk position * 8
  const int rd1 = ((4 + g) ^ q7) << 3; // kk=1
  const int cswz = ((tid & 7) ^ ((tid >> 3) & 7)) << 3;
  const int ldst = tid << 3;           // lane*16B within wave slot

  f32x4 acc[4][2];
#pragma unroll
  for (int i = 0; i < 4; ++i)
#pragma unroll
    for (int j = 0; j < 2; ++j) acc[i][j] = (f32x4){0.f, 0.f, 0.f, 0.f};

  // staging: 512 threads, row tid>>3 (0..63) + pass offset 64
  const short* Abase = A + (size_t)(m0 + (tid >> 3)) * lda + cswz;
  const short* Bbase = BT + (size_t)(n0 + (tid >> 3)) * ldb + cswz;

#define STAGE(kt, DA, DB)                                        \
  do {                                                           \
    gload16(Abase + (kt), &DA[ldst]);                            \
    gload16(Abase + (size_t)64 * lda + (kt), &DA[4096 + ldst]);  \
    gload16(Bbase + (kt), &DB[ldst]);                            \
    gload16(Bbase + (size_t)64 * ldb + (kt), &DB[4096 + ldst]);  \
  } while (0)

#define COMPUTE(SA, SB)                                                       \
  do {                                                                        \
    _Pragma("unroll") for (int kk = 0; kk < 2; ++kk) {                        \
      const int rdo = kk ? rd1 : rd0;                                         \
      bf16x8 af[4], bfv[2];                                                   \
      _Pragma("unroll") for (int mi = 0; mi < 4; ++mi)                        \
          af[mi] = *(const bf16x8*)&SA[(wr + mi * 16 + q) * 64 + rdo];        \
      _Pragma("unroll") for (int ni = 0; ni < 2; ++ni)                        \
          bfv[ni] = *(const bf16x8*)&SB[(wc + ni * 16 + q) * 64 + rdo];       \
      _Pragma("unroll") for (int mi = 0; mi < 4; ++mi)                        \
          _Pragma("unroll") for (int ni = 0; ni < 2; ++ni)                    \
              acc[mi][ni] = mfma16(bfv[ni], af[mi], acc[mi][ni]);             \
    }                                                                         \
  } while (0)

  const int nt = K >> 6;  // 6, 12, or 24 here: even, >=6
  STAGE(0, A0s, B0s);
  __syncthreads();
  for (int t = 0; t < nt; t += 2) {
    STAGE((t + 1) << 6, A1s, B1s);
    COMPUTE(A0s, B0s);
    __syncthreads();
    if (t + 2 < nt) STAGE((t + 2) << 6, A0s, B0s);
    COMPUTE(A1s, B1s);
    __syncthreads();
  }
#undef STAGE
#undef COMPUTE

  // epilogue: swapped D layout -- acc[mi][ni][r] = C[m][n] with
  // m = wr+mi*16+q, n = wc+ni*16+g*4+r  (4 consecutive n per quad)
  f32x4 bq[2];
#pragma unroll
  for (int ni = 0; ni < 2; ++ni)
    bq[ni] = bias ? *(const f32x4*)&bias[n0 + wc + ni * 16 + g * 4]
                  : (f32x4){0.f, 0.f, 0.f, 0.f};

#pragma unroll
  for (int mi = 0; mi < 4; ++mi) {
    const int grow = m0 + wr + mi * 16 + q;
    size_t orow;
    if constexpr (EPI == 2) {
      int bb = grow / 12544, rm2 = grow % 12544;
      int wi = rm2 / 49, nn = rm2 % 49;
      int wh = wi >> 4, ww = wi & 15;
      int ii = nn / 7, jj = nn % 7;
      int rr = wh * 7 + ii + 3; if (rr >= 112) rr -= 112;
      int cc = ww * 7 + jj + 3; if (cc >= 112) cc -= 112;
      orow = ((size_t)bb * 12544 + rr * 112 + cc) * 384;
    } else {
      orow = (size_t)grow * (size_t)ldo;
    }
#pragma unroll
    for (int ni = 0; ni < 2; ++ni) {
      const int gcol = n0 + wc + ni * 16 + g * 4;
      float v[4];
#pragma unroll
      for (int j = 0; j < 4; ++j) v[j] = acc[mi][ni][j] + bq[ni][j];
      if constexpr (EPI == 0) {
        u32x2 u = {cvtpk(v[0], v[1]), cvtpk(v[2], v[3])};
        *(u32x2*)&outh[orow + gcol] = u;
      } else if constexpr (EPI == 1) {
#pragma unroll
        for (int j = 0; j < 4; ++j)
          v[j] = 0.5f * v[j] * (1.f + erff(v[j] * 0.70710678118f));
        u32x2 u = {cvtpk(v[0], v[1]), cvtpk(v[2], v[3])};
        *(u32x2*)&outh[orow + gcol] = u;
      } else if constexpr (EPI == 2) {
        f32x4 r = *(const f32x4*)&resid[orow + gcol];
#pragma unroll
        for (int j = 0; j < 4; ++j) r[j] += v[j];
        *(f32x4*)&outf[orow + gcol] = r;
      } else {
        f32x4 o = *(f32x4*)&outf[orow + gcol];
#pragma unroll
        for (int j = 0; j < 4; ++j) o[j] += v[j];
        *(f32x4*)&outf[orow + gcol] = o;
      }
    }
  }
}

#define GEMM_WRAP(NAME, EPI)                                                   \
  __global__ __launch_bounds__(512) void NAME(                                 \
      const short* __restrict__ A, int lda, const short* __restrict__ BT,      \
      int ldb, const float* __restrict__ bias, int K,                          \
      short* __restrict__ outh, int ldo, float* __restrict__ outf,             \
      const float* __restrict__ resid) {                                       \
    gemm_body<EPI>(A, lda, BT, ldb, bias, K, outh, ldo, outf, resid);          \
  }
GEMM_WRAP(gemm_qkv_k, 0)
GEMM_WRAP(gemm_fc1_k, 1)
GEMM_WRAP(gemm_proj_k, 2)
GEMM_WRAP(gemm_fc2_k, 3)

// ---------------------------------------------------------------- attention
// One wave per (window, head), 4 waves/block, ZERO LDS. Swapped QK^T via
// mfma_32x32x16; in-register softmax; cvt_pk + shfl_xor(32) assembles PV
// A-frags (T12); V^T B-frags straight from global; bias+mask from table.
__global__ __launch_bounds__(256) void attn_k(const short* __restrict__ qkv,
                                              const float* __restrict__ tbl,
                                              short* __restrict__ out) {
  const int lane = threadIdx.x & 63;
  const int task = blockIdx.x * 4 + (threadIdx.x >> 6);
  const int win = task / 12;
  const int h = task - win * 12;
  const int wh = (win >> 4) & 15, ww = win & 15;
  const int cls = ((wh == 15) ? 2 : 0) + ((ww == 15) ? 1 : 0);
  const int l31 = lane & 31, h5 = lane >> 5;
  const size_t tokbase = (size_t)win * 49;
  const short* base = qkv + tokbase * 1152 + h * 32;
  const bf16x8 zero8 = {0, 0, 0, 0, 0, 0, 0, 0};

  bf16x8 kf[2][2];
#pragma unroll
  for (int mi = 0; mi < 2; ++mi) {
    int row = l31 + 32 * mi;
#pragma unroll
    for (int s = 0; s < 2; ++s)
      kf[mi][s] = (row < 49)
                      ? *(const bf16x8*)(base + (size_t)row * 1152 + 384 +
                                         16 * s + 8 * h5)
                      : zero8;
  }
  bf16x8 vf[4];
#pragma unroll
  for (int kt = 0; kt < 4; ++kt) {
#pragma unroll
    for (int e = 0; e < 8; ++e) {
      int key = 16 * kt + 8 * h5 + e;
      vf[kt][e] = (key < 49) ? base[(size_t)key * 1152 + 768 + l31] : (short)0;
    }
  }

  const float* tb = tbl + ((size_t)(cls * 12 + h) << 12);

#pragma unroll
  for (int ni = 0; ni < 2; ++ni) {
    bf16x8 qf[2];
    int qrow = l31 + 32 * ni;
#pragma unroll
    for (int s = 0; s < 2; ++s)
      qf[s] = (qrow < 49)
                  ? *(const bf16x8*)(base + (size_t)qrow * 1152 + 16 * s +
                                     8 * h5)
                  : zero8;
    f32x16 st[2];
#pragma unroll
    for (int mi = 0; mi < 2; ++mi) {
      st[mi] = mfma32(kf[mi][0], qf[0], (f32x16)(0.f));
      st[mi] = mfma32(kf[mi][1], qf[1], st[mi]);
    }
#pragma unroll
    for (int mi = 0; mi < 2; ++mi)
#pragma unroll
      for (int r = 0; r < 16; ++r) {
        int koff = (r & 3) + 8 * (r >> 2) + 4 * h5;
        st[mi][r] += tb[(size_t)(32 * mi + koff) * 64 + 32 * ni + l31];
      }
    float mx = st[0][0];
#pragma unroll
    for (int r = 1; r < 16; ++r) mx = fmaxf(mx, st[0][r]);
#pragma unroll
    for (int r = 0; r < 16; ++r) mx = fmaxf(mx, st[1][r]);
    mx = fmaxf(mx, __shfl_xor(mx, 32, 64));
    float sm = 0.f;
#pragma unroll
    for (int mi = 0; mi < 2; ++mi)
#pragma unroll
      for (int r = 0; r < 16; ++r) {
        float e = __expf(st[mi][r] - mx);
        st[mi][r] = e;
        sm += e;
      }
    sm += __shfl_xor(sm, 32, 64);
    const float rinv = 1.f / sm;
#pragma unroll
    for (int mi = 0; mi < 2; ++mi)
#pragma unroll
      for (int r = 0; r < 16; ++r) st[mi][r] *= rinv;

    f32x16 acc = (f32x16)(0.f);
#pragma unroll
    for (int kt = 0; kt < 4; ++kt) {
      const int mi = kt >> 1, b8 = (kt & 1) * 8;
      unsigned q0l = cvtpk(st[mi][b8 + 0], st[mi][b8 + 1]);
      unsigned q0h = cvtpk(st[mi][b8 + 2], st[mi][b8 + 3]);
      unsigned q1l = cvtpk(st[mi][b8 + 4], st[mi][b8 + 5]);
      unsigned q1h = cvtpk(st[mi][b8 + 6], st[mi][b8 + 7]);
      unsigned sl = h5 ? q0l : q1l, sh = h5 ? q0h : q1h;
      unsigned kl = h5 ? q1l : q0l, kh = h5 ? q1h : q0h;
      unsigned rl = (unsigned)__shfl_xor((int)sl, 32, 64);
      unsigned rh = (unsigned)__shfl_xor((int)sh, 32, 64);
      u32x4 fr;
      fr[0] = h5 ? rl : kl;
      fr[1] = h5 ? rh : kh;
      fr[2] = h5 ? kl : rl;
      fr[3] = h5 ? kh : rh;
      acc = mfma32(__builtin_bit_cast(bf16x8, fr), vf[kt], acc);
    }
#pragma unroll
    for (int r = 0; r < 16; ++r) {
      int query = 32 * ni + (r & 3) + 8 * (r >> 2) + 4 * h5;
      if (ni == 0 || query < 49)
        out[(tokbase + query) * 384 + h * 32 + l31] = f2b(acc[r]);
    }
  }
}

// ---------------------------------------------------------------- launch
extern "C" void kernel_launch(void* const* d_in, const int* in_sizes, int n_in,
                              void* d_out, int out_size, void* d_ws,
                              size_t ws_size, hipStream_t stream) {
  const float* x = (const float*)d_in[0];
  const float* n1g = (const float*)d_in[1];
  const float* n1b = (const float*)d_in[2];
  const float* qkvw = (const float*)d_in[3];
  const float* qkvb = (const float*)d_in[4];
  const float* projw = (const float*)d_in[5];
  const float* projb = (const float*)d_in[6];
  const float* rpb = (const float*)d_in[7];
  const float* n2g = (const float*)d_in[8];
  const float* n2b = (const float*)d_in[9];
  const float* fc1w = (const float*)d_in[10];
  const float* fc1b = (const float*)d_in[11];
  const float* fc2w = (const float*)d_in[12];
  const float* fc2b = (const float*)d_in[13];
  float* out = (float*)d_out;

  char* ws = (char*)d_ws;
  short* w_qkvT = (short*)(ws + 0);            // 884736 B
  short* w_projT = (short*)(ws + 884736);      // 294912 B
  short* w_fc1T = (short*)(ws + 1179648);      // 1179648 B
  short* w_fc2T = (short*)(ws + 2359296);      // 1179648 B
  float* w_qb = (float*)(ws + 3538944);        // 4608 B
  float* tbl = (float*)(ws + 3543552);         // 786432 B
  const size_t o_qkv = 4329984;
  short* qkvbuf = (short*)(ws + o_qkv);        // 462422016 B
  const size_t o_hwin = o_qkv + 462422016ull;
  short* hwin = (short*)(ws + o_hwin);         // 154140672 B
  const size_t o_fc1 = o_hwin + 154140672ull;

  int NC;
  size_t fc1_off = o_fc1;
  if (ws_size >= o_fc1 + 616562688ull) NC = 1;
  else if (ws_size >= o_fc1 + 308281344ull) NC = 2;
  else if (ws_size >= o_fc1 + 154140672ull) NC = 4;
  else { NC = 4; fc1_off = o_hwin; }
  short* fc1c = (short*)(ws + fc1_off);
  short* h2 = qkvbuf;

  const float qscale = 0.17677669529663687f;

  convT_k<<<(442368 + 255) / 256, 256, 0, stream>>>(qkvw, w_qkvT, 384, 1152, 384, qscale);
  convT_k<<<(147456 + 255) / 256, 256, 0, stream>>>(projw, w_projT, 384, 384, 0, 1.f);
  convT_k<<<(589824 + 255) / 256, 256, 0, stream>>>(fc1w, w_fc1T, 384, 1536, 0, 1.f);
  convT_k<<<(589824 + 255) / 256, 256, 0, stream>>>(fc2w, w_fc2T, 1536, 384, 0, 1.f);
  scale_bias_k<<<5, 256, 0, stream>>>(qkvb, w_qb, 1152, 384, qscale);
  biasmask_k<<<768, 256, 0, stream>>>(rpb, tbl);

  ln1_k<<<50176, 256, 0, stream>>>(x, n1g, n1b, hwin);
  gemm_qkv_k<<<dim3(9, 1568), 512, 0, stream>>>(hwin, 384, w_qkvT, 384, w_qb,
                                                384, qkvbuf, 1152, nullptr,
                                                nullptr);
  attn_k<<<12288, 256, 0, stream>>>(qkvbuf, tbl, hwin);
  gemm_proj_k<<<dim3(3, 1568), 512, 0, stream>>>(hwin, 384, w_projT, 384,
                                                 projb, 384, nullptr, 384, out,
                                                 x);
  ln2_k<<<50176, 256, 0, stream>>>(out, n2g, n2b, h2);
  const int CK = 1536 / NC;
  for (int c = 0; c < NC; ++c) {
    gemm_fc1_k<<<dim3(CK >> 7, 1568), 512, 0, stream>>>(
        h2, 384, w_fc1T + (size_t)c * CK * 384, 384, fc1b + c * CK, 384, fc1c,
        CK, nullptr, nullptr);
    gemm_fc2_k<<<dim3(3, 1568), 512, 0, stream>>>(
        fc1c, CK, w_fc2T + c * CK, 1536, (c == 0) ? fc2b : nullptr, CK,
        nullptr, 384, out, nullptr);
  }
}

// Round 12
// 1812.098 us; speedup vs baseline: 1.4952x; 1.0647x over previous
//
#include <hip/hip_runtime.h>
#include <hip/hip_bf16.h>

typedef short bf16x8 __attribute__((ext_vector_type(8)));
typedef float f32x4 __attribute__((ext_vector_type(4)));
typedef float f32x16 __attribute__((ext_vector_type(16)));
typedef unsigned int u32x4 __attribute__((ext_vector_type(4)));
typedef unsigned int u32x2 __attribute__((ext_vector_type(2)));

typedef __attribute__((address_space(1))) void gvoid;
typedef __attribute__((address_space(3))) void lvoid;

__device__ __forceinline__ short f2b(float f) {
  __hip_bfloat16 h = __float2bfloat16(f);
  return __builtin_bit_cast(short, h);
}

__device__ __forceinline__ f32x4 mfma16(bf16x8 a, bf16x8 b, f32x4 c) {
  return __builtin_amdgcn_mfma_f32_16x16x32_bf16(a, b, c, 0, 0, 0);
}

__device__ __forceinline__ f32x16 mfma32(bf16x8 a, bf16x8 b, f32x16 c) {
  return __builtin_amdgcn_mfma_f32_32x32x16_bf16(a, b, c, 0, 0, 0);
}

__device__ __forceinline__ unsigned cvtpk(float lo, float hi) {
  unsigned r;
  asm("v_cvt_pk_bf16_f32 %0, %1, %2" : "=v"(r) : "v"(lo), "v"(hi));
  return r;
}

__device__ __forceinline__ void gload16(const void* g, void* l) {
  __builtin_amdgcn_global_load_lds((const gvoid*)g, (lvoid*)l, 16, 0, 0);
}

// ---------------------------------------------------------------- weights
__global__ __launch_bounds__(256) void convT_k(const float* __restrict__ src,
                                               short* __restrict__ dst, int K,
                                               int N, int scale_cols,
                                               float scale) {
  int idx = blockIdx.x * 256 + threadIdx.x;
  if (idx >= N * K) return;
  int n = idx / K, k = idx % K;
  float v = src[(size_t)k * N + n];
  if (n < scale_cols) v *= scale;
  dst[idx] = f2b(v);
}

__global__ __launch_bounds__(256) void scale_bias_k(const float* __restrict__ src,
                                                    float* __restrict__ dst,
                                                    int n, int scale_cols,
                                                    float scale) {
  int i = blockIdx.x * 256 + threadIdx.x;
  if (i >= n) return;
  dst[i] = src[i] * (i < scale_cols ? scale : 1.f);
}

// Rel-pos bias + shift mask table, TRANSPOSED: tbl[cls][h][query][key]
// so attn's per-lane reads (query fixed, 4 consecutive keys) are f32x4.
__global__ __launch_bounds__(256) void biasmask_k(const float* __restrict__ rpb,
                                                  float* __restrict__ tbl) {
  int idx = blockIdx.x * 256 + threadIdx.x;  // < 4*12*64*64
  int key = idx & 63, q = (idx >> 6) & 63;
  int hc = idx >> 12;  // cls*12 + h
  int h = hc % 12, cls = hc / 12;
  float v;
  if (q >= 49 || key >= 49) {
    v = -1e4f;
  } else {
    int i1 = q / 7, j1 = q % 7, i2 = key / 7, j2 = key % 7;
    v = rpb[(size_t)((i1 - i2 + 6) * 13 + (j1 - j2 + 6)) * 12 + h];
    int clsh = cls >> 1, clsw = cls & 1;
    int rq = (clsh ? 1 + (i1 >= 4) : 0) * 3 + (clsw ? 1 + (j1 >= 4) : 0);
    int rk = (clsh ? 1 + (i2 >= 4) : 0) * 3 + (clsw ? 1 + (j2 >= 4) : 0);
    if (rq != rk) v -= 100.f;
  }
  tbl[idx] = v;
}

// ---------------------------------------------------------------- layernorm
template <bool GATHER>
__device__ __forceinline__ void ln_body(const float* __restrict__ x,
                                        const float* __restrict__ gw,
                                        const float* __restrict__ bw,
                                        short* __restrict__ out) {
  const int lane = threadIdx.x & 63;
  const int t = (blockIdx.x << 2) + (threadIdx.x >> 6);
  size_t srow;
  if (GATHER) {
    int bb = t / 12544, rm2 = t % 12544;
    int wi = rm2 / 49, nn = rm2 % 49;
    int wh = wi >> 4, ww = wi & 15;
    int ii = nn / 7, jj = nn % 7;
    int rr = wh * 7 + ii + 3; if (rr >= 112) rr -= 112;
    int cc = ww * 7 + jj + 3; if (cc >= 112) cc -= 112;
    srow = ((size_t)bb * 12544 + rr * 112 + cc) * 384;
  } else {
    srow = (size_t)t * 384;
  }
  const float2* src = (const float2*)(x + srow);
  const float2* g2 = (const float2*)gw;
  const float2* b2 = (const float2*)bw;
  float2 u[3];
  float s = 0.f, ss = 0.f;
#pragma unroll
  for (int k = 0; k < 3; ++k) {
    u[k] = src[lane + (k << 6)];
    s += u[k].x + u[k].y;
    ss += u[k].x * u[k].x + u[k].y * u[k].y;
  }
#pragma unroll
  for (int m = 1; m < 64; m <<= 1) {
    s += __shfl_xor(s, m, 64);
    ss += __shfl_xor(ss, m, 64);
  }
  const float mean = s * (1.f / 384.f);
  const float var = ss * (1.f / 384.f) - mean * mean;
  const float rstd = rsqrtf(var + 1e-5f);
  unsigned* o = (unsigned*)(out + (size_t)t * 384);
#pragma unroll
  for (int k = 0; k < 3; ++k) {
    int c = lane + (k << 6);
    float2 gv = g2[c], bv = b2[c];
    unsigned lo = (unsigned short)f2b((u[k].x - mean) * rstd * gv.x + bv.x);
    unsigned hi = (unsigned short)f2b((u[k].y - mean) * rstd * gv.y + bv.y);
    o[c] = lo | (hi << 16);
  }
}

__global__ __launch_bounds__(256) void ln1_k(const float* __restrict__ x,
                                             const float* __restrict__ gw,
                                             const float* __restrict__ bw,
                                             short* __restrict__ out) {
  ln_body<true>(x, gw, bw, out);
}
__global__ __launch_bounds__(256) void ln2_k(const float* __restrict__ x,
                                             const float* __restrict__ gw,
                                             const float* __restrict__ bw,
                                             short* __restrict__ out) {
  ln_body<false>(x, gw, bw, out);
}

// ---------------------------------------------------------------- GEMM
// 128x128 tile, BK=64, 512 threads / 8 waves (2x4 grid, wave tile
// 64x32), static dbuf (64KB LDS, 2 blk/CU, 16 waves/CU), r9 swizzle
// (conflicts=0), swapped-operand mfma (vectorized epilogue). r11-best.
template <int EPI>
__device__ __forceinline__ void gemm_body(
    const short* __restrict__ A, int lda, const short* __restrict__ BT,
    int ldb, const float* __restrict__ bias, int K, short* __restrict__ outh,
    int ldo, float* __restrict__ outf, const float* __restrict__ resid) {
  __shared__ __align__(16) short A0s[8192], B0s[8192];
  __shared__ __align__(16) short A1s[8192], B1s[8192];
  const int tid = threadIdx.x;
  const int gx = gridDim.x;
  int lin = blockIdx.y * gx + blockIdx.x;
  const int cpx = (gx * gridDim.y) >> 3;
  lin = (lin & 7) * cpx + (lin >> 3);
  const int m0 = (lin / gx) << 7, n0 = (lin % gx) << 7;
  const int lane = tid & 63;
  const int wave = tid >> 6;           // 0..7
  const int wr = (wave >> 2) << 6;     // 0 or 64
  const int wc = (wave & 3) << 5;      // 0,32,64,96
  const int g = lane >> 4, q = lane & 15;
  const int q7 = q & 7;
  const int rd0 = ((g) ^ q7) << 3;
  const int rd1 = ((4 + g) ^ q7) << 3;
  const int cswz = ((tid & 7) ^ ((tid >> 3) & 7)) << 3;
  const int ldst = tid << 3;

  f32x4 acc[4][2];
#pragma unroll
  for (int i = 0; i < 4; ++i)
#pragma unroll
    for (int j = 0; j < 2; ++j) acc[i][j] = (f32x4){0.f, 0.f, 0.f, 0.f};

  const short* Abase = A + (size_t)(m0 + (tid >> 3)) * lda + cswz;
  const short* Bbase = BT + (size_t)(n0 + (tid >> 3)) * ldb + cswz;

#define STAGE(kt, DA, DB)                                        \
  do {                                                           \
    gload16(Abase + (kt), &DA[ldst]);                            \
    gload16(Abase + (size_t)64 * lda + (kt), &DA[4096 + ldst]);  \
    gload16(Bbase + (kt), &DB[ldst]);                            \
    gload16(Bbase + (size_t)64 * ldb + (kt), &DB[4096 + ldst]);  \
  } while (0)

#define COMPUTE(SA, SB)                                                       \
  do {                                                                        \
    _Pragma("unroll") for (int kk = 0; kk < 2; ++kk) {                        \
      const int rdo = kk ? rd1 : rd0;                                         \
      bf16x8 af[4], bfv[2];                                                   \
      _Pragma("unroll") for (int mi = 0; mi < 4; ++mi)                        \
          af[mi] = *(const bf16x8*)&SA[(wr + mi * 16 + q) * 64 + rdo];        \
      _Pragma("unroll") for (int ni = 0; ni < 2; ++ni)                        \
          bfv[ni] = *(const bf16x8*)&SB[(wc + ni * 16 + q) * 64 + rdo];       \
      _Pragma("unroll") for (int mi = 0; mi < 4; ++mi)                        \
          _Pragma("unroll") for (int ni = 0; ni < 2; ++ni)                    \
              acc[mi][ni] = mfma16(bfv[ni], af[mi], acc[mi][ni]);             \
    }                                                                         \
  } while (0)

  const int nt = K >> 6;  // 6 or 24 here: even, >=6
  STAGE(0, A0s, B0s);
  __syncthreads();
  for (int t = 0; t < nt; t += 2) {
    STAGE((t + 1) << 6, A1s, B1s);
    COMPUTE(A0s, B0s);
    __syncthreads();
    if (t + 2 < nt) STAGE((t + 2) << 6, A0s, B0s);
    COMPUTE(A1s, B1s);
    __syncthreads();
  }
#undef STAGE
#undef COMPUTE

  f32x4 bq[2];
#pragma unroll
  for (int ni = 0; ni < 2; ++ni)
    bq[ni] = bias ? *(const f32x4*)&bias[n0 + wc + ni * 16 + g * 4]
                  : (f32x4){0.f, 0.f, 0.f, 0.f};

#pragma unroll
  for (int mi = 0; mi < 4; ++mi) {
    const int grow = m0 + wr + mi * 16 + q;
    size_t orow;
    if constexpr (EPI == 2) {
      int bb = grow / 12544, rm2 = grow % 12544;
      int wi = rm2 / 49, nn = rm2 % 49;
      int wh = wi >> 4, ww = wi & 15;
      int ii = nn / 7, jj = nn % 7;
      int rr = wh * 7 + ii + 3; if (rr >= 112) rr -= 112;
      int cc = ww * 7 + jj + 3; if (cc >= 112) cc -= 112;
      orow = ((size_t)bb * 12544 + rr * 112 + cc) * 384;
    } else {
      orow = (size_t)grow * (size_t)ldo;
    }
#pragma unroll
    for (int ni = 0; ni < 2; ++ni) {
      const int gcol = n0 + wc + ni * 16 + g * 4;
      float v[4];
#pragma unroll
      for (int j = 0; j < 4; ++j) v[j] = acc[mi][ni][j] + bq[ni][j];
      if constexpr (EPI == 0) {
        u32x2 u = {cvtpk(v[0], v[1]), cvtpk(v[2], v[3])};
        *(u32x2*)&outh[orow + gcol] = u;
      } else if constexpr (EPI == 1) {
#pragma unroll
        for (int j = 0; j < 4; ++j)
          v[j] = 0.5f * v[j] * (1.f + erff(v[j] * 0.70710678118f));
        u32x2 u = {cvtpk(v[0], v[1]), cvtpk(v[2], v[3])};
        *(u32x2*)&outh[orow + gcol] = u;
      } else if constexpr (EPI == 2) {
        f32x4 r = *(const f32x4*)&resid[orow + gcol];
#pragma unroll
        for (int j = 0; j < 4; ++j) r[j] += v[j];
        *(f32x4*)&outf[orow + gcol] = r;
      } else {
        f32x4 o = *(f32x4*)&outf[orow + gcol];
#pragma unroll
        for (int j = 0; j < 4; ++j) o[j] += v[j];
        *(f32x4*)&outf[orow + gcol] = o;
      }
    }
  }
}

#define GEMM_WRAP(NAME, EPI)                                                   \
  __global__ __launch_bounds__(512) void NAME(                                 \
      const short* __restrict__ A, int lda, const short* __restrict__ BT,      \
      int ldb, const float* __restrict__ bias, int K,                          \
      short* __restrict__ outh, int ldo, float* __restrict__ outf,             \
      const float* __restrict__ resid) {                                       \
    gemm_body<EPI>(A, lda, BT, ldb, bias, K, outh, ldo, outf, resid);          \
  }
GEMM_WRAP(gemm_qkv_k, 0)
GEMM_WRAP(gemm_fc1_k, 1)
GEMM_WRAP(gemm_proj_k, 2)
GEMM_WRAP(gemm_fc2_k, 3)

// ---------------------------------------------------------------- attention
// One wave per (window, head), 4 waves/block, ZERO LDS. Swapped QK^T via
// mfma_32x32x16; in-register softmax; cvt_pk + shfl_xor(32) assembles PV
// A-frags (T12); V^T B-frags straight from global; bias+mask from
// TRANSPOSED table ([query][key]) read as f32x4 (16 vec loads vs 64
// scalar -- the kernel is VMEM-issue/latency bound).
__global__ __launch_bounds__(256) void attn_k(const short* __restrict__ qkv,
                                              const float* __restrict__ tbl,
                                              short* __restrict__ out) {
  const int lane = threadIdx.x & 63;
  const int task = blockIdx.x * 4 + (threadIdx.x >> 6);
  const int win = task / 12;
  const int h = task - win * 12;
  const int wh = (win >> 4) & 15, ww = win & 15;
  const int cls = ((wh == 15) ? 2 : 0) + ((ww == 15) ? 1 : 0);
  const int l31 = lane & 31, h5 = lane >> 5;
  const size_t tokbase = (size_t)win * 49;
  const short* base = qkv + tokbase * 1152 + h * 32;
  const bf16x8 zero8 = {0, 0, 0, 0, 0, 0, 0, 0};

  bf16x8 kf[2][2];
#pragma unroll
  for (int mi = 0; mi < 2; ++mi) {
    int row = l31 + 32 * mi;
#pragma unroll
    for (int s = 0; s < 2; ++s)
      kf[mi][s] = (row < 49)
                      ? *(const bf16x8*)(base + (size_t)row * 1152 + 384 +
                                         16 * s + 8 * h5)
                      : zero8;
  }
  bf16x8 vf[4];
#pragma unroll
  for (int kt = 0; kt < 4; ++kt) {
#pragma unroll
    for (int e = 0; e < 8; ++e) {
      int key = 16 * kt + 8 * h5 + e;
      vf[kt][e] = (key < 49) ? base[(size_t)key * 1152 + 768 + l31] : (short)0;
    }
  }

  const float* tb = tbl + ((size_t)(cls * 12 + h) << 12);

#pragma unroll
  for (int ni = 0; ni < 2; ++ni) {
    bf16x8 qf[2];
    int qrow = l31 + 32 * ni;
#pragma unroll
    for (int s = 0; s < 2; ++s)
      qf[s] = (qrow < 49)
                  ? *(const bf16x8*)(base + (size_t)qrow * 1152 + 16 * s +
                                     8 * h5)
                  : zero8;
    f32x16 st[2];
#pragma unroll
    for (int mi = 0; mi < 2; ++mi) {
      st[mi] = mfma32(kf[mi][0], qf[0], (f32x16)(0.f));
      st[mi] = mfma32(kf[mi][1], qf[1], st[mi]);
    }
    // + bias/mask: query = 32ni+l31 (lane-fixed), keys consecutive -> f32x4
#pragma unroll
    for (int mi = 0; mi < 2; ++mi) {
      const float* bp = tb + (size_t)(32 * ni + l31) * 64 + 32 * mi + 4 * h5;
#pragma unroll
      for (int j = 0; j < 4; ++j) {
        f32x4 b4 = *(const f32x4*)(bp + 8 * j);
#pragma unroll
        for (int e = 0; e < 4; ++e) st[mi][4 * j + e] += b4[e];
      }
    }
    float mx = st[0][0];
#pragma unroll
    for (int r = 1; r < 16; ++r) mx = fmaxf(mx, st[0][r]);
#pragma unroll
    for (int r = 0; r < 16; ++r) mx = fmaxf(mx, st[1][r]);
    mx = fmaxf(mx, __shfl_xor(mx, 32, 64));
    float sm = 0.f;
#pragma unroll
    for (int mi = 0; mi < 2; ++mi)
#pragma unroll
      for (int r = 0; r < 16; ++r) {
        float e = __expf(st[mi][r] - mx);
        st[mi][r] = e;
        sm += e;
      }
    sm += __shfl_xor(sm, 32, 64);
    const float rinv = 1.f / sm;
#pragma unroll
    for (int mi = 0; mi < 2; ++mi)
#pragma unroll
      for (int r = 0; r < 16; ++r) st[mi][r] *= rinv;

    f32x16 acc = (f32x16)(0.f);
#pragma unroll
    for (int kt = 0; kt < 4; ++kt) {
      const int mi = kt >> 1, b8 = (kt & 1) * 8;
      unsigned q0l = cvtpk(st[mi][b8 + 0], st[mi][b8 + 1]);
      unsigned q0h = cvtpk(st[mi][b8 + 2], st[mi][b8 + 3]);
      unsigned q1l = cvtpk(st[mi][b8 + 4], st[mi][b8 + 5]);
      unsigned q1h = cvtpk(st[mi][b8 + 6], st[mi][b8 + 7]);
      unsigned sl = h5 ? q0l : q1l, sh = h5 ? q0h : q1h;
      unsigned kl = h5 ? q1l : q0l, kh = h5 ? q1h : q0h;
      unsigned rl = (unsigned)__shfl_xor((int)sl, 32, 64);
      unsigned rh = (unsigned)__shfl_xor((int)sh, 32, 64);
      u32x4 fr;
      fr[0] = h5 ? rl : kl;
      fr[1] = h5 ? rh : kh;
      fr[2] = h5 ? kl : rl;
      fr[3] = h5 ? kh : rh;
      acc = mfma32(__builtin_bit_cast(bf16x8, fr), vf[kt], acc);
    }
#pragma unroll
    for (int r = 0; r < 16; ++r) {
      int query = 32 * ni + (r & 3) + 8 * (r >> 2) + 4 * h5;
      if (ni == 0 || query < 49)
        out[(tokbase + query) * 384 + h * 32 + l31] = f2b(acc[r]);
    }
  }
}

// ---------------------------------------------------------------- launch
extern "C" void kernel_launch(void* const* d_in, const int* in_sizes, int n_in,
                              void* d_out, int out_size, void* d_ws,
                              size_t ws_size, hipStream_t stream) {
  const float* x = (const float*)d_in[0];
  const float* n1g = (const float*)d_in[1];
  const float* n1b = (const float*)d_in[2];
  const float* qkvw = (const float*)d_in[3];
  const float* qkvb = (const float*)d_in[4];
  const float* projw = (const float*)d_in[5];
  const float* projb = (const float*)d_in[6];
  const float* rpb = (const float*)d_in[7];
  const float* n2g = (const float*)d_in[8];
  const float* n2b = (const float*)d_in[9];
  const float* fc1w = (const float*)d_in[10];
  const float* fc1b = (const float*)d_in[11];
  const float* fc2w = (const float*)d_in[12];
  const float* fc2b = (const float*)d_in[13];
  float* out = (float*)d_out;

  char* ws = (char*)d_ws;
  short* w_qkvT = (short*)(ws + 0);            // 884736 B
  short* w_projT = (short*)(ws + 884736);      // 294912 B
  short* w_fc1T = (short*)(ws + 1179648);      // 1179648 B
  short* w_fc2T = (short*)(ws + 2359296);      // 1179648 B
  float* w_qb = (float*)(ws + 3538944);        // 4608 B
  float* tbl = (float*)(ws + 3543552);         // 786432 B
  const size_t o_qkv = 4329984;
  short* qkvbuf = (short*)(ws + o_qkv);        // 462422016 B
  const size_t o_hwin = o_qkv + 462422016ull;
  short* hwin = (short*)(ws + o_hwin);         // 154140672 B
  // M-slab MLP: fc1 slab buffer (50176 x 1536 bf16 = 154140672 B) overlays
  // hwin -- hwin is dead after proj; zero extra ws needed.
  short* fc1c = hwin;
  short* h2 = qkvbuf;  // LN2 out overlays qkv buffer (dead after attn)

  const float qscale = 0.17677669529663687f;

  convT_k<<<(442368 + 255) / 256, 256, 0, stream>>>(qkvw, w_qkvT, 384, 1152, 384, qscale);
  convT_k<<<(147456 + 255) / 256, 256, 0, stream>>>(projw, w_projT, 384, 384, 0, 1.f);
  convT_k<<<(589824 + 255) / 256, 256, 0, stream>>>(fc1w, w_fc1T, 384, 1536, 0, 1.f);
  convT_k<<<(589824 + 255) / 256, 256, 0, stream>>>(fc2w, w_fc2T, 1536, 384, 0, 1.f);
  scale_bias_k<<<5, 256, 0, stream>>>(qkvb, w_qb, 1152, 384, qscale);
  biasmask_k<<<768, 256, 0, stream>>>(rpb, tbl);

  ln1_k<<<50176, 256, 0, stream>>>(x, n1g, n1b, hwin);
  gemm_qkv_k<<<dim3(9, 1568), 512, 0, stream>>>(hwin, 384, w_qkvT, 384, w_qb,
                                                384, qkvbuf, 1152, nullptr,
                                                nullptr);
  attn_k<<<12288, 256, 0, stream>>>(qkvbuf, tbl, hwin);
  gemm_proj_k<<<dim3(3, 1568), 512, 0, stream>>>(hwin, 384, w_projT, 384,
                                                 projb, 384, nullptr, 384, out,
                                                 x);
  ln2_k<<<50176, 256, 0, stream>>>(out, n2g, n2b, h2);
  // MLP over 4 M-slabs of 50176 rows: fc1 full-width (slab L3-resident),
  // fc2 immediately consumes it with K=1536 (24 K-tiles), out RMW'd once.
  for (int s = 0; s < 4; ++s) {
    const size_t ro = (size_t)s * 50176;
    gemm_fc1_k<<<dim3(12, 392), 512, 0, stream>>>(
        h2 + ro * 384, 384, w_fc1T, 384, fc1b, 384, fc1c, 1536, nullptr,
        nullptr);
    gemm_fc2_k<<<dim3(3, 392), 512, 0, stream>>>(
        fc1c, 1536, w_fc2T, 1536, fc2b, 1536, nullptr, 384, out + ro * 384,
        nullptr);
  }
}